// Round 1
// baseline (1495.069 us; speedup 1.0000x reference)
//
#include <hip/hip_runtime.h>

#define KNB 32
#define CIN 128
#define CH 64
#define COUT 256
#define BN_EPS 1e-5f
#define CONV_GRID 1024
#define AGG_GRID 256

static __device__ __forceinline__ float leakyf(float v){ return v >= 0.0f ? v : 0.1f*v; }

// ---------- Gram of features: G[128][128] += f f^T, s[128] += f ----------
__global__ __launch_bounds__(256) void gram128_kernel(const float* __restrict__ feat, int N,
                                                      float* __restrict__ G, float* __restrict__ s)
{
    __shared__ float row[CIN];
    int tid = threadIdx.x;
    int tr = tid >> 4, tc = tid & 15;
    float acc[8][8] = {};
    float ps = 0.f;
    for (int n = blockIdx.x; n < N; n += gridDim.x){
        __syncthreads();
        if (tid < CIN) row[tid] = feat[(size_t)n*CIN + tid];
        __syncthreads();
        float rv[8], cv[8];
        #pragma unroll
        for (int i=0;i<8;++i) rv[i] = row[tr*8+i];
        #pragma unroll
        for (int j=0;j<8;++j) cv[j] = row[tc*8+j];
        #pragma unroll
        for (int i=0;i<8;++i)
            #pragma unroll
            for (int j=0;j<8;++j) acc[i][j] += rv[i]*cv[j];
        if (tid < CIN) ps += row[tid];
    }
    for (int i=0;i<8;++i)
        for (int j=0;j<8;++j)
            atomicAdd(&G[(tr*8+i)*CIN + tc*8+j], acc[i][j]);
    if (tid < CIN) atomicAdd(&s[tid], ps);
}

// ---------- 64-wide Gram, optional per-channel affine+leaky transform, optional weights ----------
__global__ __launch_bounds__(256) void gram64_kernel(const float* __restrict__ src,
                                                     const float* __restrict__ wts,
                                                     const float* __restrict__ ta,
                                                     const float* __restrict__ tc,
                                                     float* __restrict__ outrow,
                                                     float* __restrict__ G, float* __restrict__ s, int N)
{
    __shared__ float row[CH];
    __shared__ float wrow[CH];
    int tid = threadIdx.x;
    int tr = tid >> 4, tcl = tid & 15;
    float acc[4][4] = {};
    float ps = 0.f;
    for (int n = blockIdx.x; n < N; n += gridDim.x){
        __syncthreads();
        if (tid < CH){
            float v = src[(size_t)n*CH + tid];
            if (ta){
                v = ta[tid]*v + tc[tid];
                v = leakyf(v);
                if (outrow) outrow[(size_t)n*CH + tid] = v;
            }
            float w = wts ? wts[n] : 1.0f;
            row[tid] = v; wrow[tid] = w*v;
        }
        __syncthreads();
        float rv[4], cv[4];
        #pragma unroll
        for (int i=0;i<4;++i) rv[i] = wrow[tr*4+i];
        #pragma unroll
        for (int j=0;j<4;++j) cv[j] = row[tcl*4+j];
        #pragma unroll
        for (int i=0;i<4;++i)
            #pragma unroll
            for (int j=0;j<4;++j) acc[i][j] += rv[i]*cv[j];
        if (tid < CH) ps += wrow[tid];
    }
    for (int i=0;i<4;++i)
        for (int j=0;j<4;++j)
            atomicAdd(&G[(tr*4+i)*CH + tcl*4+j], acc[i][j]);
    if (tid < CH) atomicAdd(&s[tid], ps);
}

// ---------- derive BN affine (a,c) for y = X@W from Gram/colsum of X ----------
__global__ void finalize_lin_bn(const float* __restrict__ G, const float* __restrict__ s,
                                const float* __restrict__ W, const float* __restrict__ g,
                                const float* __restrict__ b, float invcnt, int D, int M,
                                float* __restrict__ a, float* __restrict__ c)
{
    int o = blockIdx.x, lane = threadIdx.x;   // 64 threads
    float pm = 0.f, pq = 0.f;
    for (int i = lane; i < D; i += 64){
        float wi = W[i*M + o];
        pm += s[i]*wi;
        float t = 0.f;
        for (int j = 0; j < D; ++j) t += G[i*D + j]*W[j*M + o];
        pq += wi*t;
    }
    #pragma unroll
    for (int off = 32; off; off >>= 1){
        pm += __shfl_down(pm, off);
        pq += __shfl_down(pq, off);
    }
    if (lane == 0){
        float m  = pm*invcnt;
        float E2 = pq*invcnt;
        float var = E2 - m*m;
        float ai = g[o]*rsqrtf(var + BN_EPS);
        a[o] = ai; c[o] = b[o] - m*ai;
    }
}

// ---------- derive BN affine from per-block partial (sum,sumsq) slabs ----------
__global__ __launch_bounds__(256) void finalize_direct(const float* __restrict__ part, int nrows,
                                                       const float* __restrict__ g, const float* __restrict__ b,
                                                       float invcnt, float* __restrict__ a, float* __restrict__ c)
{
    int tid = threadIdx.x; int t = tid & 63, seg = tid >> 6;
    float s = 0.f, ss = 0.f;
    for (int r = seg; r < nrows; r += 4){ s += part[r*128 + t]; ss += part[r*128 + 64 + t]; }
    __shared__ float r1[256], r2[256];
    r1[tid] = s; r2[tid] = ss;
    __syncthreads();
    if (tid < 64){
        s  = r1[tid] + r1[tid+64] + r1[tid+128] + r1[tid+192];
        ss = r2[tid] + r2[tid+64] + r2[tid+128] + r2[tid+192];
        float m = s*invcnt, var = ss*invcnt - m*m;
        float ai = g[tid]*rsqrtf(var + BN_EPS);
        a[tid] = ai; c[tid] = b[tid] - m*ai;
    }
}

// ---------- neighbor-index histogram (float counts, exact integers) ----------
__global__ void hist_kernel(const int* __restrict__ inds, int total, int N, float* __restrict__ cnt)
{
    int i = blockIdx.x*256 + threadIdx.x;
    if (i < total){
        int ix = inds[i];
        if ((unsigned)ix < (unsigned)N) atomicAdd(&cnt[ix], 1.0f);
    }
}

// ---------- x = leaky(a1*(feat@W)+c1), tiled GEMM 64 rows/block ----------
__global__ __launch_bounds__(256) void unary1_gemm_kernel(const float* __restrict__ feat,
    const float* __restrict__ W, const float* __restrict__ a1, const float* __restrict__ c1,
    float* __restrict__ xout, int N)
{
    __shared__ float rows[64*129];
    __shared__ float wt[CIN*CH];
    int tid = threadIdx.x;
    for (int i = tid; i < CIN*CH; i += 256) wt[i] = a1[i & 63]*W[i];
    int nb = blockIdx.x*64;
    for (int i = tid; i < 2048; i += 256){
        int r = i >> 5, c4 = i & 31;
        int n = nb + r;
        float4 v = make_float4(0.f,0.f,0.f,0.f);
        if (n < N) v = ((const float4*)feat)[(size_t)n*32 + c4];
        rows[r*129 + c4*4+0]=v.x; rows[r*129 + c4*4+1]=v.y;
        rows[r*129 + c4*4+2]=v.z; rows[r*129 + c4*4+3]=v.w;
    }
    __syncthreads();
    int tn = tid & 15, to = tid >> 4;
    float acc[4][4] = {};
    for (int c = 0; c < CIN; ++c){
        float rv[4], wv[4];
        #pragma unroll
        for (int i=0;i<4;++i) rv[i] = rows[(tn*4+i)*129 + c];
        #pragma unroll
        for (int j=0;j<4;++j) wv[j] = wt[c*CH + to*4 + j];
        #pragma unroll
        for (int i=0;i<4;++i)
            #pragma unroll
            for (int j=0;j<4;++j) acc[i][j] += rv[i]*wv[j];
    }
    #pragma unroll
    for (int i=0;i<4;++i){
        int n = nb + tn*4 + i;
        if (n >= N) continue;
        #pragma unroll
        for (int j=0;j<4;++j){
            int o = to*4 + j;
            xout[(size_t)n*CH + o] = leakyf(acc[i][j] + c1[o]);
        }
    }
}

// ---------- fused gather -> conv0 -> bn0+leaky -> conv1 x nb_x -> stats + max/min ----------
__global__ __launch_bounds__(512) void conv_msg_kernel(
    const float* __restrict__ x, const float* __restrict__ qp, const float* __restrict__ sp,
    const int* __restrict__ inds, const float* __restrict__ W0, const float* __restrict__ W1,
    const float* __restrict__ a0p, const float* __restrict__ c0p,
    float* __restrict__ mx, float* __restrict__ mn, float* __restrict__ msgpart, int N)
{
    __shared__ float sW0[CH*CH];
    __shared__ float sW1[CH*CH*3];
    __shared__ __align__(16) float sY[KNB*CH];
    __shared__ float sK0[KNB*CH];
    __shared__ float sNX[KNB*4];
    __shared__ int   sIdx[KNB];
    int tid = threadIdx.x;
    int d = tid & 63, kg = tid >> 6;        // kg in 0..7, each thread owns k = kg + 8*i
    for (int i = tid; i < CH*CH;   i += 512) sW0[i] = W0[i];
    for (int i = tid; i < CH*CH*3; i += 512) sW1[i] = W1[i];
    float a0 = a0p[d], c0 = c0p[d];
    float psum = 0.f, pss = 0.f;
    for (int n = blockIdx.x; n < N; n += gridDim.x){
        __syncthreads();                                      // protect sY/sIdx/sNX reuse
        if (tid < KNB) sIdx[tid] = inds[(size_t)n*KNB + tid];
        __syncthreads();
        if (tid < KNB){
            int ix = sIdx[tid];
            float sx=0.f, sy=0.f, sz=0.f;
            if ((unsigned)ix < (unsigned)N){ sx = sp[ix*3]; sy = sp[ix*3+1]; sz = sp[ix*3+2]; }
            sNX[tid*4+0] = sx - qp[n*3+0];
            sNX[tid*4+1] = sy - qp[n*3+1];
            sNX[tid*4+2] = sz - qp[n*3+2];
        }
        {
            int k = tid >> 4, c4 = tid & 15;
            int ix = sIdx[k];
            float4 v = make_float4(0.f,0.f,0.f,0.f);
            if ((unsigned)ix < (unsigned)N) v = ((const float4*)x)[(size_t)ix*16 + c4];
            ((float4*)sY)[k*16 + c4] = v;
        }
        __syncthreads();
        // ---- stage 2: z0 = nb_y @ W0 ; k0 = leaky(a0*z0+c0) ----
        float acc0=0.f, acc1=0.f, acc2=0.f, acc3=0.f;
        #pragma unroll 4
        for (int c = 0; c < CH; ++c){
            float w = sW0[c*CH + d];
            acc0 += sY[(kg   )*CH + c]*w;
            acc1 += sY[(kg+ 8)*CH + c]*w;
            acc2 += sY[(kg+16)*CH + c]*w;
            acc3 += sY[(kg+24)*CH + c]*w;
        }
        sK0[(kg   )*CH + d] = leakyf(a0*acc0 + c0);
        sK0[(kg+ 8)*CH + d] = leakyf(a0*acc1 + c0);
        sK0[(kg+16)*CH + d] = leakyf(a0*acc2 + c0);
        sK0[(kg+24)*CH + d] = leakyf(a0*acc3 + c0);
        float dx0=sNX[(kg   )*4], dy0=sNX[(kg   )*4+1], dz0=sNX[(kg   )*4+2];
        float dx1=sNX[(kg+ 8)*4], dy1=sNX[(kg+ 8)*4+1], dz1=sNX[(kg+ 8)*4+2];
        float dx2=sNX[(kg+16)*4], dy2=sNX[(kg+16)*4+1], dz2=sNX[(kg+16)*4+2];
        float dx3=sNX[(kg+24)*4], dy3=sNX[(kg+24)*4+1], dz3=sNX[(kg+24)*4+2];
        __syncthreads();
        // ---- stage 3: msg[k][h] = sum_dd k0[k][dd]*(W1[dd][3h:3h+3] . nb_x[k]) , h == d ----
        float m0=0.f, m1=0.f, m2=0.f, m3=0.f;
        #pragma unroll 4
        for (int dd = 0; dd < CH; ++dd){
            float w0v = sW1[dd*192 + 3*d    ];
            float w1v = sW1[dd*192 + 3*d + 1];
            float w2v = sW1[dd*192 + 3*d + 2];
            float t0 = w0v*dx0 + w1v*dy0 + w2v*dz0;
            float t1 = w0v*dx1 + w1v*dy1 + w2v*dz1;
            float t2 = w0v*dx2 + w1v*dy2 + w2v*dz2;
            float t3 = w0v*dx3 + w1v*dy3 + w2v*dz3;
            m0 += sK0[(kg   )*CH + dd]*t0;
            m1 += sK0[(kg+ 8)*CH + dd]*t1;
            m2 += sK0[(kg+16)*CH + dd]*t2;
            m3 += sK0[(kg+24)*CH + dd]*t3;
        }
        // ---- stage 4: per-thread stats over its 4 k's, then cross-wave combine ----
        float vmx = fmaxf(fmaxf(m0,m1), fmaxf(m2,m3));
        float vmn = fminf(fminf(m0,m1), fminf(m2,m3));
        float s4  = m0+m1+m2+m3;
        float ss4 = m0*m0 + m1*m1 + m2*m2 + m3*m3;
        ((float4*)sY)[kg*64 + d] = make_float4(vmx, vmn, s4, ss4);
        __syncthreads();
        if (tid < CH){
            float gmx=-1e30f, gmn=1e30f, gs=0.f, gss=0.f;
            #pragma unroll
            for (int g = 0; g < 8; ++g){
                float4 p = ((const float4*)sY)[g*64 + tid];
                gmx = fmaxf(gmx, p.x); gmn = fminf(gmn, p.y);
                gs += p.z; gss += p.w;
            }
            mx[(size_t)n*CH + tid] = gmx;
            mn[(size_t)n*CH + tid] = gmn;
            psum += gs; pss += gss;
        }
    }
    if (tid < CH){
        msgpart[(size_t)blockIdx.x*128 + tid]      = psum;
        msgpart[(size_t)blockIdx.x*128 + 64 + tid] = pss;
    }
}

// ---------- agg = leaky(a1m*(max or min)+c1m) ; bnc stat partials ----------
__global__ __launch_bounds__(256) void msg_agg_kernel(const float* __restrict__ mx, const float* __restrict__ mn,
    const float* __restrict__ a1m, const float* __restrict__ c1m,
    float* __restrict__ agg, float* __restrict__ aggpart, int total)
{
    int tid = threadIdx.x; int h = tid & 63;
    float ah = a1m[h], ch = c1m[h];
    bool useMax = (ah >= 0.f);
    float ps = 0.f, pss = 0.f;
    for (int i = blockIdx.x*256 + tid; i < total; i += gridDim.x*256){
        float sel = useMax ? mx[i] : mn[i];
        float v = leakyf(ah*sel + ch);
        agg[i] = v; ps += v; pss += v*v;
    }
    __shared__ float r1[256], r2[256];
    r1[tid] = ps; r2[tid] = pss;
    __syncthreads();
    if (tid < 64){
        float s  = r1[tid] + r1[tid+64] + r1[tid+128] + r1[tid+192];
        float ss = r2[tid] + r2[tid+64] + r2[tid+128] + r2[tid+192];
        aggpart[(size_t)blockIdx.x*128 + tid]      = s;
        aggpart[(size_t)blockIdx.x*128 + 64 + tid] = ss;
    }
}

// ---------- out = leaky( a2o*(a2@W2)+c2o + asc*(feat@Wsc)+csc ) ----------
__global__ __launch_bounds__(256) void final_gemm_kernel(const float* __restrict__ feat, const float* __restrict__ a2,
    const float* __restrict__ Wsc, const float* __restrict__ W2,
    const float* __restrict__ asc, const float* __restrict__ csc,
    const float* __restrict__ a2o, const float* __restrict__ c2o,
    float* __restrict__ out, int N)
{
    __shared__ float rows[64*193];
    __shared__ float wt[192*64];
    int tid = threadIdx.x;
    int nb = blockIdx.x*64;
    for (int i = tid; i < 2048; i += 256){
        int r = i >> 5, c4 = i & 31;
        int n = nb + r;
        float4 v = make_float4(0.f,0.f,0.f,0.f);
        if (n < N) v = ((const float4*)feat)[(size_t)n*32 + c4];
        rows[r*193 + c4*4+0]=v.x; rows[r*193 + c4*4+1]=v.y;
        rows[r*193 + c4*4+2]=v.z; rows[r*193 + c4*4+3]=v.w;
    }
    for (int i = tid; i < 1024; i += 256){
        int r = i >> 4, c4 = i & 15;
        int n = nb + r;
        float4 v = make_float4(0.f,0.f,0.f,0.f);
        if (n < N) v = ((const float4*)a2)[(size_t)n*16 + c4];
        rows[r*193 + 128 + c4*4+0]=v.x; rows[r*193 + 128 + c4*4+1]=v.y;
        rows[r*193 + 128 + c4*4+2]=v.z; rows[r*193 + 128 + c4*4+3]=v.w;
    }
    int tn = tid & 15, to = tid >> 4;
    for (int ot = 0; ot < 4; ++ot){
        __syncthreads();
        for (int i = tid; i < 12288; i += 256){
            int r = i >> 6, cc = i & 63, o = ot*64 + cc;
            wt[i] = (r < 128) ? asc[o]*Wsc[r*COUT + o] : a2o[o]*W2[(r-128)*COUT + o];
        }
        __syncthreads();
        float acc[4][4] = {};
        for (int c = 0; c < 192; ++c){
            float rv[4], wv[4];
            #pragma unroll
            for (int i=0;i<4;++i) rv[i] = rows[(tn*4+i)*193 + c];
            #pragma unroll
            for (int j=0;j<4;++j) wv[j] = wt[c*64 + to*4 + j];
            #pragma unroll
            for (int i=0;i<4;++i)
                #pragma unroll
                for (int j=0;j<4;++j) acc[i][j] += rv[i]*wv[j];
        }
        #pragma unroll
        for (int i=0;i<4;++i){
            int n = nb + tn*4 + i;
            if (n >= N) continue;
            #pragma unroll
            for (int j=0;j<4;++j){
                int o = ot*64 + to*4 + j;
                out[(size_t)n*COUT + o] = leakyf(acc[i][j] + csc[o] + c2o[o]);
            }
        }
    }
}

extern "C" void kernel_launch(void* const* d_in, const int* in_sizes, int n_in,
                              void* d_out, int out_size, void* d_ws, size_t ws_size,
                              hipStream_t stream)
{
    const float* feat = (const float*)d_in[0];
    const float* qp   = (const float*)d_in[1];
    const float* sp   = (const float*)d_in[2];
    const int*   inds = (const int*)d_in[3];
    const float* Wu1  = (const float*)d_in[4];
    const float* g1   = (const float*)d_in[5];
    const float* b1   = (const float*)d_in[6];
    const float* W0   = (const float*)d_in[7];
    const float* gb0  = (const float*)d_in[8];
    const float* bb0  = (const float*)d_in[9];
    const float* W1   = (const float*)d_in[10];
    const float* gb1  = (const float*)d_in[11];
    const float* bb1  = (const float*)d_in[12];
    const float* gbc  = (const float*)d_in[13];
    const float* bbc  = (const float*)d_in[14];
    const float* Wu2  = (const float*)d_in[15];
    const float* g2   = (const float*)d_in[16];
    const float* b2   = (const float*)d_in[17];
    const float* Wsc  = (const float*)d_in[18];
    const float* gsc  = (const float*)d_in[19];
    const float* bsc  = (const float*)d_in[20];

    const int N = in_sizes[0] / CIN;           // 20000

    float* ws   = (float*)d_ws;
    float* XtX  = ws;                          // 16384
    float* fsum = XtX + 16384;                 // 128
    float* G0   = fsum + 128;                  // 4096
    float* s0   = G0 + 4096;                   // 64
    float* G2   = s0 + 64;                     // 4096
    float* s2   = G2 + 4096;                   // 64
    float* cnt  = s2 + 64;                     // N
    float* prm  = cnt + N;                     // 1536 params
    float* a1 = prm,      *c1 = prm+64,  *a0 = prm+128,  *c0 = prm+192;
    float* a1m = prm+256, *c1m = prm+320, *abnc = prm+384, *cbnc = prm+448;
    float* asc = prm+512, *csc = prm+768, *a2o = prm+1024, *c2o = prm+1280;
    float* msgpart = prm + 1536;                   // CONV_GRID*128
    float* aggpart = msgpart + CONV_GRID*128;      // AGG_GRID*128
    float* xbuf = aggpart + AGG_GRID*128;          // N*64
    float* mxb  = xbuf + (size_t)N*CH;             // N*64
    float* mnb  = mxb  + (size_t)N*CH;             // N*64
    float* aggb = mnb  + (size_t)N*CH;             // N*64
    float* a2b  = aggb + (size_t)N*CH;             // N*64

    size_t statsBytes = (size_t)(16384 + 128 + 4096 + 64 + 4096 + 64 + N) * sizeof(float);
    hipMemsetAsync(d_ws, 0, statsBytes, stream);

    const int nTiles = (N + 63) / 64;

    gram128_kernel<<<64, 256, 0, stream>>>(feat, N, XtX, fsum);
    finalize_lin_bn<<<CH, 64, 0, stream>>>(XtX, fsum, Wu1, g1, b1, 1.0f/N, CIN, CH, a1, c1);
    finalize_lin_bn<<<COUT, 64, 0, stream>>>(XtX, fsum, Wsc, gsc, bsc, 1.0f/N, CIN, COUT, asc, csc);
    unary1_gemm_kernel<<<nTiles, 256, 0, stream>>>(feat, Wu1, a1, c1, xbuf, N);
    hist_kernel<<<(N*KNB + 255)/256, 256, 0, stream>>>(inds, N*KNB, N, cnt);
    gram64_kernel<<<64, 256, 0, stream>>>(xbuf, cnt, nullptr, nullptr, nullptr, G0, s0, N);
    finalize_lin_bn<<<CH, 64, 0, stream>>>(G0, s0, W0, gb0, bb0, 1.0f/((float)N*KNB), CH, CH, a0, c0);
    conv_msg_kernel<<<CONV_GRID, 512, 0, stream>>>(xbuf, qp, sp, inds, W0, W1, a0, c0, mxb, mnb, msgpart, N);
    finalize_direct<<<1, 256, 0, stream>>>(msgpart, CONV_GRID, gb1, bb1, 1.0f/((float)N*KNB), a1m, c1m);
    msg_agg_kernel<<<AGG_GRID, 256, 0, stream>>>(mxb, mnb, a1m, c1m, aggb, aggpart, N*CH);
    finalize_direct<<<1, 256, 0, stream>>>(aggpart, AGG_GRID, gbc, bbc, 1.0f/N, abnc, cbnc);
    gram64_kernel<<<64, 256, 0, stream>>>(aggb, nullptr, abnc, cbnc, a2b, G2, s2, N);
    finalize_lin_bn<<<COUT, 64, 0, stream>>>(G2, s2, Wu2, g2, b2, 1.0f/N, CH, COUT, a2o, c2o);
    final_gemm_kernel<<<nTiles, 256, 0, stream>>>(feat, a2b, Wsc, Wu2, asc, csc, a2o, c2o, (float*)d_out, N);
}

// Round 2
// 593.613 us; speedup vs baseline: 2.5186x; 2.5186x over previous
//
#include <hip/hip_runtime.h>

#define KNB 32
#define CIN 128
#define CH 64
#define COUT 256
#define BN_EPS 1e-5f
#define CONV_GRID 256
#define AGG_GRID 256
#define GRAM_GRID 128

typedef __attribute__((ext_vector_type(8))) short bf16x8;
typedef __attribute__((ext_vector_type(4))) float f32x4;

static __device__ __forceinline__ float leakyf(float v){ return fmaxf(v, 0.1f*v); }

static __device__ __forceinline__ unsigned short f2bf(float f){
    unsigned u = __float_as_uint(f);
    u += 0x7FFFu + ((u >> 16) & 1u);
    return (unsigned short)(u >> 16);
}

static __device__ __forceinline__ unsigned cvtpk(float lo, float hi){
    unsigned r;
    asm("v_cvt_pk_bf16_f32 %0, %1, %2" : "=v"(r) : "v"(lo), "v"(hi));
    return r;
}

// ---------- Gram of features: G[128][128] += f f^T, s[128] += f ----------
__global__ __launch_bounds__(256) void gram128_kernel(const float* __restrict__ feat, int N,
                                                      float* __restrict__ G, float* __restrict__ s)
{
    __shared__ float row[CIN];
    int tid = threadIdx.x;
    int tr = tid >> 4, tc = tid & 15;
    float acc[8][8] = {};
    float ps = 0.f;
    for (int n = blockIdx.x; n < N; n += gridDim.x){
        __syncthreads();
        if (tid < CIN) row[tid] = feat[(size_t)n*CIN + tid];
        __syncthreads();
        float rv[8], cv[8];
        #pragma unroll
        for (int i=0;i<8;++i) rv[i] = row[tr*8+i];
        #pragma unroll
        for (int j=0;j<8;++j) cv[j] = row[tc*8+j];
        #pragma unroll
        for (int i=0;i<8;++i)
            #pragma unroll
            for (int j=0;j<8;++j) acc[i][j] += rv[i]*cv[j];
        if (tid < CIN) ps += row[tid];
    }
    for (int i=0;i<8;++i)
        for (int j=0;j<8;++j)
            atomicAdd(&G[(tr*8+i)*CIN + tc*8+j], acc[i][j]);
    if (tid < CIN) atomicAdd(&s[tid], ps);
}

// ---------- 64-wide Gram, optional affine+leaky transform (bf16 out), optional weights ----------
__global__ __launch_bounds__(256) void gram64_kernel(const float* __restrict__ src,
                                                     const float* __restrict__ wts,
                                                     const float* __restrict__ ta,
                                                     const float* __restrict__ tc,
                                                     ushort* __restrict__ outrow,
                                                     float* __restrict__ G, float* __restrict__ s, int N)
{
    __shared__ float row[CH];
    __shared__ float wrow[CH];
    int tid = threadIdx.x;
    int tr = tid >> 4, tcl = tid & 15;
    float acc[4][4] = {};
    float ps = 0.f;
    for (int n = blockIdx.x; n < N; n += gridDim.x){
        __syncthreads();
        if (tid < CH){
            float v = src[(size_t)n*CH + tid];
            if (ta){
                v = ta[tid]*v + tc[tid];
                v = leakyf(v);
                if (outrow) outrow[(size_t)n*CH + tid] = f2bf(v);
            }
            float w = wts ? wts[n] : 1.0f;
            row[tid] = v; wrow[tid] = w*v;
        }
        __syncthreads();
        float rv[4], cv[4];
        #pragma unroll
        for (int i=0;i<4;++i) rv[i] = wrow[tr*4+i];
        #pragma unroll
        for (int j=0;j<4;++j) cv[j] = row[tcl*4+j];
        #pragma unroll
        for (int i=0;i<4;++i)
            #pragma unroll
            for (int j=0;j<4;++j) acc[i][j] += rv[i]*cv[j];
        if (tid < CH) ps += wrow[tid];
    }
    for (int i=0;i<4;++i)
        for (int j=0;j<4;++j)
            atomicAdd(&G[(tr*4+i)*CH + tcl*4+j], acc[i][j]);
    if (tid < CH) atomicAdd(&s[tid], ps);
}

// ---------- derive BN affine (a,c) for y = X@W from Gram/colsum of X ----------
__global__ void finalize_lin_bn(const float* __restrict__ G, const float* __restrict__ s,
                                const float* __restrict__ W, const float* __restrict__ g,
                                const float* __restrict__ b, float invcnt, int D, int M,
                                float* __restrict__ a, float* __restrict__ c)
{
    int o = blockIdx.x, lane = threadIdx.x;   // 64 threads
    float pm = 0.f, pq = 0.f;
    for (int i = lane; i < D; i += 64){
        float wi = W[i*M + o];
        pm += s[i]*wi;
        float t = 0.f;
        for (int j = 0; j < D; ++j) t += G[i*D + j]*W[j*M + o];
        pq += wi*t;
    }
    #pragma unroll
    for (int off = 32; off; off >>= 1){
        pm += __shfl_down(pm, off);
        pq += __shfl_down(pq, off);
    }
    if (lane == 0){
        float m  = pm*invcnt;
        float E2 = pq*invcnt;
        float var = E2 - m*m;
        float ai = g[o]*rsqrtf(var + BN_EPS);
        a[o] = ai; c[o] = b[o] - m*ai;
    }
}

// ---------- derive BN affine from per-block partial (sum,sumsq) slabs ----------
__global__ __launch_bounds__(256) void finalize_direct(const float* __restrict__ part, int nrows,
                                                       const float* __restrict__ g, const float* __restrict__ b,
                                                       float invcnt, float* __restrict__ a, float* __restrict__ c)
{
    int tid = threadIdx.x; int t = tid & 63, seg = tid >> 6;
    float s = 0.f, ss = 0.f;
    for (int r = seg; r < nrows; r += 4){ s += part[r*128 + t]; ss += part[r*128 + 64 + t]; }
    __shared__ float r1[256], r2[256];
    r1[tid] = s; r2[tid] = ss;
    __syncthreads();
    if (tid < 64){
        s  = r1[tid] + r1[tid+64] + r1[tid+128] + r1[tid+192];
        ss = r2[tid] + r2[tid+64] + r2[tid+128] + r2[tid+192];
        float m = s*invcnt, var = ss*invcnt - m*m;
        float ai = g[tid]*rsqrtf(var + BN_EPS);
        a[tid] = ai; c[tid] = b[tid] - m*ai;
    }
}

// ---------- neighbor-index histogram ----------
__global__ void hist_kernel(const int* __restrict__ inds, int total, int N, float* __restrict__ cnt)
{
    int i = blockIdx.x*256 + threadIdx.x;
    if (i < total){
        int ix = inds[i];
        if ((unsigned)ix < (unsigned)N) atomicAdd(&cnt[ix], 1.0f);
    }
}

// ---------- fp32 -> bf16 bulk convert (x4 vectorized) ----------
__global__ void cvt_bf16x4_kernel(const float* __restrict__ src, ushort* __restrict__ dst, int total4)
{
    int i = blockIdx.x*256 + threadIdx.x;
    if (i < total4){
        float4 v = ((const float4*)src)[i];
        uint2 p;
        p.x = (unsigned)f2bf(v.x) | ((unsigned)f2bf(v.y) << 16);
        p.y = (unsigned)f2bf(v.z) | ((unsigned)f2bf(v.w) << 16);
        ((uint2*)dst)[i] = p;
    }
}

// ---------- x = leaky(a1*(feat@W)+c1): fp32 out + bf16 out ----------
__global__ __launch_bounds__(256) void unary1_gemm_kernel(const float* __restrict__ feat,
    const float* __restrict__ W, const float* __restrict__ a1, const float* __restrict__ c1,
    float* __restrict__ xout, ushort* __restrict__ xbf, int N)
{
    __shared__ float rows[64*129];
    __shared__ float wt[CIN*CH];
    int tid = threadIdx.x;
    for (int i = tid; i < CIN*CH; i += 256) wt[i] = a1[i & 63]*W[i];
    int nb = blockIdx.x*64;
    for (int i = tid; i < 2048; i += 256){
        int r = i >> 5, c4 = i & 31;
        int n = nb + r;
        float4 v = make_float4(0.f,0.f,0.f,0.f);
        if (n < N) v = ((const float4*)feat)[(size_t)n*32 + c4];
        rows[r*129 + c4*4+0]=v.x; rows[r*129 + c4*4+1]=v.y;
        rows[r*129 + c4*4+2]=v.z; rows[r*129 + c4*4+3]=v.w;
    }
    __syncthreads();
    int tn = tid & 15, to = tid >> 4;
    float acc[4][4] = {};
    for (int c = 0; c < CIN; ++c){
        float rv[4], wv[4];
        #pragma unroll
        for (int i=0;i<4;++i) rv[i] = rows[(tn*4+i)*129 + c];
        #pragma unroll
        for (int j=0;j<4;++j) wv[j] = wt[c*CH + to*4 + j];
        #pragma unroll
        for (int i=0;i<4;++i)
            #pragma unroll
            for (int j=0;j<4;++j) acc[i][j] += rv[i]*wv[j];
    }
    #pragma unroll
    for (int i=0;i<4;++i){
        int n = nb + tn*4 + i;
        if (n >= N) continue;
        #pragma unroll
        for (int j=0;j<4;++j){
            int o = to*4 + j;
            float v = leakyf(acc[i][j] + c1[o]);
            xout[(size_t)n*CH + o] = v;
            xbf[(size_t)n*CH + o] = f2bf(v);
        }
    }
}

// ---------- prep: W0T scaled by a0, bf16: w0t[d][c] = a0[d]*W0[c][d] ----------
__global__ void prep_w0_kernel(const float* __restrict__ W0, const float* __restrict__ a0,
                               ushort* __restrict__ w0t)
{
    int i = blockIdx.x*256 + threadIdx.x;
    if (i < CH*CH){ int d = i >> 6, c = i & 63; w0t[i] = f2bf(a0[d]*W0[c*CH + d]); }
}

// ---------- prep: w1s[(c*64+h)][dd] = W1[dd][3h+c], bf16 ----------
__global__ void prep_w1_kernel(const float* __restrict__ W1, ushort* __restrict__ w1s)
{
    int i = blockIdx.x*256 + threadIdx.x;
    if (i < 192*CH){
        int r = i >> 6, dd = i & 63;
        int c = r >> 6, h = r & 63;
        w1s[i] = f2bf(W1[dd*192 + 3*h + c]);
    }
}

// ---------- prep: wcat[o][kk] = scaled concat(Wsc,Wu2)^T bf16 ; ccomb = csc+c2o ----------
__global__ void prep_final_kernel(const float* __restrict__ Wsc, const float* __restrict__ Wu2,
    const float* __restrict__ asc, const float* __restrict__ csc,
    const float* __restrict__ a2o, const float* __restrict__ c2o,
    ushort* __restrict__ wcat, float* __restrict__ ccomb)
{
    int i = blockIdx.x*256 + threadIdx.x;
    if (i < COUT*192){
        int o = i / 192, kk = i % 192;
        float v = (kk < CIN) ? asc[o]*Wsc[kk*COUT + o] : a2o[o]*Wu2[(kk-CIN)*COUT + o];
        wcat[i] = f2bf(v);
    }
    if (i < COUT) ccomb[i] = csc[i] + c2o[i];
}

// ---------- fused MFMA: gather -> conv0(swapped) -> bn0+leaky -> nbx-scaled k0c -> conv1 -> stats ----------
__global__ __launch_bounds__(512) void conv_msg_mfma(
    const ushort* __restrict__ xbf, const float* __restrict__ qp, const float* __restrict__ sp,
    const int* __restrict__ inds, const ushort* __restrict__ w0t, const ushort* __restrict__ w1s,
    const float* __restrict__ c0p,
    float* __restrict__ mx, float* __restrict__ mn, float* __restrict__ msgpart, int N)
{
    __shared__ unsigned char SM[24576 + 8*12288];   // Wstage (swizzled) + per-wave k0c tiles
    int tid = threadIdx.x;
    int warp = tid >> 6, lane = tid & 63;
    int l15 = lane & 15, g = lane >> 4;
    // stage w1s (192x64 bf16) into LDS, XOR-swizzled by row&7
    for (int ch = tid; ch < 1536; ch += 512){
        int r = ch >> 3, c16 = ch & 7;
        uint4 v = ((const uint4*)w1s)[ch];
        *(uint4*)(SM + r*128 + ((c16*16) ^ ((r&7)<<4))) = v;
    }
    // loop-invariant W0T fragments + c0
    bf16x8 wf[8];
    #pragma unroll
    for (int mt=0;mt<4;++mt)
        #pragma unroll
        for (int s=0;s<2;++s)
            wf[mt*2+s] = *(const bf16x8*)(w0t + (mt*16+l15)*CH + s*32 + g*8);
    float c0r[16];
    #pragma unroll
    for (int mt=0;mt<4;++mt)
        #pragma unroll
        for (int q=0;q<4;++q)
            c0r[mt*4+q] = c0p[mt*16 + g*4 + q];
    unsigned char* k0base = SM + 24576 + warp*12288;
    unsigned swz = (unsigned)((l15 & 7) << 4);
    float ps[4] = {0,0,0,0}, pss[4] = {0,0,0,0};
    const int nwaves = gridDim.x*8;
    const f32x4 z4 = {0.f,0.f,0.f,0.f};
    __syncthreads();

    for (int n = blockIdx.x*8 + warp; n < N; n += nwaves){
        int ix0 = inds[n*KNB + l15];
        int ix1 = inds[n*KNB + 16 + l15];
        if ((unsigned)ix0 > (unsigned)N) ix0 = N;
        if ((unsigned)ix1 > (unsigned)N) ix1 = N;
        float qx = qp[n*3+0], qy = qp[n*3+1], qz = qp[n*3+2];
        float nbv[2][3];
        if (ix0 < N){ nbv[0][0]=sp[ix0*3]-qx; nbv[0][1]=sp[ix0*3+1]-qy; nbv[0][2]=sp[ix0*3+2]-qz; }
        else        { nbv[0][0]=-qx; nbv[0][1]=-qy; nbv[0][2]=-qz; }
        if (ix1 < N){ nbv[1][0]=sp[ix1*3]-qx; nbv[1][1]=sp[ix1*3+1]-qy; nbv[1][2]=sp[ix1*3+2]-qz; }
        else        { nbv[1][0]=-qx; nbv[1][1]=-qy; nbv[1][2]=-qz; }
        // gather nb_y fragments (B operand of swapped conv0), 16B per lane
        bf16x8 xf0a = *(const bf16x8*)(xbf + (size_t)ix0*CH +      g*8);
        bf16x8 xf0b = *(const bf16x8*)(xbf + (size_t)ix0*CH + 32 + g*8);
        bf16x8 xf1a = *(const bf16x8*)(xbf + (size_t)ix1*CH +      g*8);
        bf16x8 xf1b = *(const bf16x8*)(xbf + (size_t)ix1*CH + 32 + g*8);
        // conv0: z0^T = (a0.W0^T) @ nb_y^T   (M=d:4 tiles, N=k:2 tiles, K=c:2 steps)
        f32x4 acc0[8];
        #pragma unroll
        for (int i=0;i<8;++i) acc0[i] = z4;
        #pragma unroll
        for (int mt=0;mt<4;++mt){
            acc0[mt*2+0] = __builtin_amdgcn_mfma_f32_16x16x32_bf16(wf[mt*2+0], xf0a, acc0[mt*2+0], 0,0,0);
            acc0[mt*2+0] = __builtin_amdgcn_mfma_f32_16x16x32_bf16(wf[mt*2+1], xf0b, acc0[mt*2+0], 0,0,0);
            acc0[mt*2+1] = __builtin_amdgcn_mfma_f32_16x16x32_bf16(wf[mt*2+0], xf1a, acc0[mt*2+1], 0,0,0);
            acc0[mt*2+1] = __builtin_amdgcn_mfma_f32_16x16x32_bf16(wf[mt*2+1], xf1b, acc0[mt*2+1], 0,0,0);
        }
        // bn0 (+c0) + leaky, scale by nbx[c], pack bf16, write k0c[c][k][d] (swizzled)
        #pragma unroll
        for (int mt=0;mt<4;++mt){
            #pragma unroll
            for (int ntk=0;ntk<2;++ntk){
                f32x4 a = acc0[mt*2+ntk];
                float v0 = leakyf(a[0] + c0r[mt*4+0]);
                float v1 = leakyf(a[1] + c0r[mt*4+1]);
                float v2 = leakyf(a[2] + c0r[mt*4+2]);
                float v3 = leakyf(a[3] + c0r[mt*4+3]);
                #pragma unroll
                for (int c=0;c<3;++c){
                    float w = nbv[ntk][c];
                    uint2 pk;
                    pk.x = cvtpk(v0*w, v1*w);
                    pk.y = cvtpk(v2*w, v3*w);
                    *(uint2*)(k0base + (c*32 + ntk*16 + l15)*128 + ((unsigned)(mt*32 + g*8) ^ swz)) = pk;
                }
            }
        }
        // conv1: msg = sum_c (k0*nbx_c) @ W1_c   (M=k:2 tiles, N=h:4 tiles, K=dd:2 steps, c:3)
        f32x4 acc1[8];
        #pragma unroll
        for (int i=0;i<8;++i) acc1[i] = z4;
        #pragma unroll
        for (int c=0;c<3;++c){
            #pragma unroll
            for (int ks=0;ks<2;++ks){
                unsigned co = ((unsigned)(ks*64 + g*16)) ^ swz;
                bf16x8 a0f = *(const bf16x8*)(k0base + (c*32 +      l15)*128 + co);
                bf16x8 a1f = *(const bf16x8*)(k0base + (c*32 + 16 + l15)*128 + co);
                #pragma unroll
                for (int nt=0;nt<4;++nt){
                    bf16x8 bfr = *(const bf16x8*)(SM + (c*64 + nt*16 + l15)*128 + co);
                    acc1[0*4+nt] = __builtin_amdgcn_mfma_f32_16x16x32_bf16(a0f, bfr, acc1[0*4+nt], 0,0,0);
                    acc1[1*4+nt] = __builtin_amdgcn_mfma_f32_16x16x32_bf16(a1f, bfr, acc1[1*4+nt], 0,0,0);
                }
            }
        }
        // reduce over k: per-lane 8 vals, then butterfly over lane>>4 groups
        #pragma unroll
        for (int nt=0;nt<4;++nt){
            float vmx = -3.4e38f, vmn = 3.4e38f, s = 0.f, ssq = 0.f;
            #pragma unroll
            for (int mtk=0;mtk<2;++mtk){
                f32x4 a = acc1[mtk*4+nt];
                #pragma unroll
                for (int q=0;q<4;++q){
                    float v = a[q];
                    vmx = fmaxf(vmx, v); vmn = fminf(vmn, v);
                    s += v; ssq += v*v;
                }
            }
            vmx = fmaxf(vmx, __shfl_xor(vmx, 16)); vmn = fminf(vmn, __shfl_xor(vmn, 16));
            s  += __shfl_xor(s, 16);               ssq += __shfl_xor(ssq, 16);
            vmx = fmaxf(vmx, __shfl_xor(vmx, 32)); vmn = fminf(vmn, __shfl_xor(vmn, 32));
            s  += __shfl_xor(s, 32);               ssq += __shfl_xor(ssq, 32);
            if (lane < 16){
                mx[(size_t)n*CH + nt*16 + l15] = vmx;
                mn[(size_t)n*CH + nt*16 + l15] = vmn;
                ps[nt] += s; pss[nt] += ssq;
            }
        }
    }
    // block-level stat reduction (reuse LDS)
    __syncthreads();
    float* red = (float*)SM;
    if (lane < 16){
        #pragma unroll
        for (int nt=0;nt<4;++nt){
            red[warp*128 + nt*16 + l15]        = ps[nt];
            red[1024 + warp*128 + nt*16 + l15] = pss[nt];
        }
    }
    __syncthreads();
    if (tid < 64){
        float s = 0.f, ssq = 0.f;
        #pragma unroll
        for (int w8=0;w8<8;++w8){ s += red[w8*128 + tid]; ssq += red[1024 + w8*128 + tid]; }
        msgpart[(size_t)blockIdx.x*128 + tid]      = s;
        msgpart[(size_t)blockIdx.x*128 + 64 + tid] = ssq;
    }
}

// ---------- agg = leaky(a1m*(max or min)+c1m) ; bnc stat partials ----------
__global__ __launch_bounds__(256) void msg_agg_kernel(const float* __restrict__ mx, const float* __restrict__ mn,
    const float* __restrict__ a1m, const float* __restrict__ c1m,
    float* __restrict__ agg, float* __restrict__ aggpart, int total)
{
    int tid = threadIdx.x; int h = tid & 63;
    float ah = a1m[h], ch = c1m[h];
    bool useMax = (ah >= 0.f);
    float ps = 0.f, pss = 0.f;
    for (int i = blockIdx.x*256 + tid; i < total; i += gridDim.x*256){
        float sel = useMax ? mx[i] : mn[i];
        float v = leakyf(ah*sel + ch);
        agg[i] = v; ps += v; pss += v*v;
    }
    __shared__ float r1[256], r2[256];
    r1[tid] = ps; r2[tid] = pss;
    __syncthreads();
    if (tid < 64){
        float s  = r1[tid] + r1[tid+64] + r1[tid+128] + r1[tid+192];
        float ss = r2[tid] + r2[tid+64] + r2[tid+128] + r2[tid+192];
        aggpart[(size_t)blockIdx.x*128 + tid]      = s;
        aggpart[(size_t)blockIdx.x*128 + 64 + tid] = ss;
    }
}

// ---------- final: out = leaky( [featbf|a2b2] @ wcat^T + ccomb ), bf16 MFMA ----------
__global__ __launch_bounds__(256) void final_mfma_kernel(
    const ushort* __restrict__ featbf, const ushort* __restrict__ a2b2,
    const ushort* __restrict__ wcat, const float* __restrict__ ccomb,
    float* __restrict__ out, int N)
{
    int tid = threadIdx.x, warp = tid >> 6, lane = tid & 63;
    int l15 = lane & 15, g = lane >> 4;
    int row0 = blockIdx.x*64 + warp*16;
    const f32x4 z4 = {0.f,0.f,0.f,0.f};
    f32x4 acc[16];
    #pragma unroll
    for (int i=0;i<16;++i) acc[i] = z4;
    int r = row0 + l15;
    bool ok = r < N;
    #pragma unroll
    for (int s=0;s<6;++s){
        bf16x8 af = {0,0,0,0,0,0,0,0};
        if (ok){
            const ushort* srcp = (s < 4) ? (featbf + (size_t)r*CIN + s*32 + g*8)
                                         : (a2b2  + (size_t)r*CH + (s-4)*32 + g*8);
            af = *(const bf16x8*)srcp;
        }
        #pragma unroll
        for (int nt=0;nt<16;++nt){
            bf16x8 bfr = *(const bf16x8*)(wcat + (nt*16+l15)*192 + s*32 + g*8);
            acc[nt] = __builtin_amdgcn_mfma_f32_16x16x32_bf16(af, bfr, acc[nt], 0,0,0);
        }
    }
    #pragma unroll
    for (int nt=0;nt<16;++nt){
        float cc = ccomb[nt*16 + l15];
        #pragma unroll
        for (int q=0;q<4;++q){
            int rr = row0 + g*4 + q;
            if (rr < N){
                float v = acc[nt][q] + cc;
                out[(size_t)rr*COUT + nt*16 + l15] = leakyf(v);
            }
        }
    }
}

extern "C" void kernel_launch(void* const* d_in, const int* in_sizes, int n_in,
                              void* d_out, int out_size, void* d_ws, size_t ws_size,
                              hipStream_t stream)
{
    const float* feat = (const float*)d_in[0];
    const float* qp   = (const float*)d_in[1];
    const float* sp   = (const float*)d_in[2];
    const int*   inds = (const int*)d_in[3];
    const float* Wu1  = (const float*)d_in[4];
    const float* g1   = (const float*)d_in[5];
    const float* b1   = (const float*)d_in[6];
    const float* W0   = (const float*)d_in[7];
    const float* gb0  = (const float*)d_in[8];
    const float* bb0  = (const float*)d_in[9];
    const float* W1   = (const float*)d_in[10];
    const float* gb1  = (const float*)d_in[11];
    const float* bb1  = (const float*)d_in[12];
    const float* gbc  = (const float*)d_in[13];
    const float* bbc  = (const float*)d_in[14];
    const float* Wu2  = (const float*)d_in[15];
    const float* g2   = (const float*)d_in[16];
    const float* b2   = (const float*)d_in[17];
    const float* Wsc  = (const float*)d_in[18];
    const float* gsc  = (const float*)d_in[19];
    const float* bsc  = (const float*)d_in[20];

    const int N = in_sizes[0] / CIN;           // 20000

    float* ws   = (float*)d_ws;
    float* XtX  = ws;                              // 16384
    float* fsum = XtX + 16384;                     // 128
    float* G0   = fsum + 128;                      // 4096
    float* s0   = G0 + 4096;                       // 64
    float* G2   = s0 + 64;                         // 4096
    float* s2   = G2 + 4096;                       // 64
    float* cnt  = s2 + 64;                         // N
    float* prm  = cnt + N;                         // 1536 params
    float* a1 = prm,      *c1 = prm+64,  *a0 = prm+128,  *c0 = prm+192;
    float* a1m = prm+256, *c1m = prm+320, *abnc = prm+384, *cbnc = prm+448;
    float* asc = prm+512, *csc = prm+768, *a2o = prm+1024, *c2o = prm+1280;
    float* msgpart = prm + 1536;                   // CONV_GRID*128
    float* aggpart = msgpart + CONV_GRID*128;      // AGG_GRID*128
    float* xbuf = aggpart + AGG_GRID*128;          // N*64 f32
    float* mxb  = xbuf + (size_t)N*CH;             // N*64
    float* mnb  = mxb  + (size_t)N*CH;             // N*64
    float* aggb = mnb  + (size_t)N*CH;             // N*64
    float* p    = aggb + (size_t)N*CH;
    ushort* xbf    = (ushort*)p;  p += (size_t)(N+1)*CH/2;   // (N+1)*64 bf16
    ushort* featbf = (ushort*)p;  p += (size_t)N*CIN/2;      // N*128 bf16
    ushort* a2b2   = (ushort*)p;  p += (size_t)N*CH/2;       // N*64 bf16
    ushort* w0t    = (ushort*)p;  p += 2048;                 // 64*64 bf16
    ushort* w1s    = (ushort*)p;  p += 6144;                 // 192*64 bf16
    ushort* wcat   = (ushort*)p;  p += 24576;                // 256*192 bf16
    float*  ccomb  = p;                                      // 256 f32

    size_t statsBytes = (size_t)(16384 + 128 + 4096 + 64 + 4096 + 64 + N) * sizeof(float);
    hipMemsetAsync(d_ws, 0, statsBytes, stream);
    hipMemsetAsync((void*)(xbf + (size_t)N*CH), 0, CH*sizeof(ushort), stream);  // zero shadow row

    const int nTiles = (N + 63) / 64;

    cvt_bf16x4_kernel<<<(N*CIN/4 + 255)/256, 256, 0, stream>>>(feat, featbf, N*CIN/4);
    prep_w1_kernel<<<48, 256, 0, stream>>>(W1, w1s);
    gram128_kernel<<<GRAM_GRID, 256, 0, stream>>>(feat, N, XtX, fsum);
    finalize_lin_bn<<<CH, 64, 0, stream>>>(XtX, fsum, Wu1, g1, b1, 1.0f/N, CIN, CH, a1, c1);
    finalize_lin_bn<<<COUT, 64, 0, stream>>>(XtX, fsum, Wsc, gsc, bsc, 1.0f/N, CIN, COUT, asc, csc);
    unary1_gemm_kernel<<<nTiles, 256, 0, stream>>>(feat, Wu1, a1, c1, xbuf, xbf, N);
    hist_kernel<<<(N*KNB + 255)/256, 256, 0, stream>>>(inds, N*KNB, N, cnt);
    gram64_kernel<<<GRAM_GRID, 256, 0, stream>>>(xbuf, cnt, nullptr, nullptr, nullptr, G0, s0, N);
    finalize_lin_bn<<<CH, 64, 0, stream>>>(G0, s0, W0, gb0, bb0, 1.0f/((float)N*KNB), CH, CH, a0, c0);
    prep_w0_kernel<<<16, 256, 0, stream>>>(W0, a0, w0t);
    conv_msg_mfma<<<CONV_GRID, 512, 0, stream>>>(xbf, qp, sp, inds, w0t, w1s, c0, mxb, mnb, msgpart, N);
    finalize_direct<<<1, 256, 0, stream>>>(msgpart, CONV_GRID, gb1, bb1, 1.0f/((float)N*KNB), a1m, c1m);
    msg_agg_kernel<<<AGG_GRID, 256, 0, stream>>>(mxb, mnb, a1m, c1m, aggb, aggpart, N*CH);
    finalize_direct<<<1, 256, 0, stream>>>(aggpart, AGG_GRID, gbc, bbc, 1.0f/N, abnc, cbnc);
    gram64_kernel<<<GRAM_GRID, 256, 0, stream>>>(aggb, nullptr, abnc, cbnc, a2b2, G2, s2, N);
    finalize_lin_bn<<<COUT, 64, 0, stream>>>(G2, s2, Wu2, g2, b2, 1.0f/N, CH, COUT, a2o, c2o);
    prep_final_kernel<<<192, 256, 0, stream>>>(Wsc, Wu2, asc, csc, a2o, c2o, wcat, ccomb);
    final_mfma_kernel<<<(N+63)/64, 256, 0, stream>>>(featbf, a2b2, wcat, ccomb, (float*)d_out, N);
}

// Round 3
// 455.502 us; speedup vs baseline: 3.2822x; 1.3032x over previous
//
#include <hip/hip_runtime.h>

#define KNB 32
#define CIN 128
#define CH 64
#define COUT 256
#define BN_EPS 1e-5f
#define CONV_GRID 256
#define AGG_GRID 256
#define G128_GRID 128
#define G128_CHUNK 32
#define G64_GRID 64
#define G64_CHUNK 64

typedef __attribute__((ext_vector_type(8))) short bf16x8;
typedef __attribute__((ext_vector_type(4))) float f32x4;

static __device__ __forceinline__ float leakyf(float v){ return fmaxf(v, 0.1f*v); }

static __device__ __forceinline__ unsigned short f2bf(float f){
    unsigned u = __float_as_uint(f);
    u += 0x7FFFu + ((u >> 16) & 1u);
    return (unsigned short)(u >> 16);
}

static __device__ __forceinline__ unsigned cvtpk(float lo, float hi){
    unsigned r;
    asm("v_cvt_pk_bf16_f32 %0, %1, %2" : "=v"(r) : "v"(lo), "v"(hi));
    return r;
}

// ---------- Gram of features: G[128][128] += f f^T, s[128] += f (chunked LDS) ----------
__global__ __launch_bounds__(256) void gram128_kernel(const float* __restrict__ feat, int N,
                                                      float* __restrict__ G, float* __restrict__ s)
{
    __shared__ float X[G128_CHUNK][CIN];   // 16 KB
    int tid = threadIdx.x;
    int tr = tid >> 4, tc = tid & 15;
    float acc[8][8] = {};
    float ps = 0.f;
    for (int base = blockIdx.x*G128_CHUNK; base < N; base += gridDim.x*G128_CHUNK){
        __syncthreads();
        for (int i = tid; i < G128_CHUNK*32; i += 256){
            int r = i >> 5, c4 = i & 31;
            int n = base + r;
            float4 v = make_float4(0.f,0.f,0.f,0.f);
            if (n < N) v = ((const float4*)feat)[(size_t)n*32 + c4];
            X[r][c4*4+0]=v.x; X[r][c4*4+1]=v.y; X[r][c4*4+2]=v.z; X[r][c4*4+3]=v.w;
        }
        __syncthreads();
        int lim = min(G128_CHUNK, N - base);
        #pragma unroll 4
        for (int rr = 0; rr < lim; ++rr){
            float rv[8], cv[8];
            #pragma unroll
            for (int i=0;i<8;++i) rv[i] = X[rr][tr*8+i];
            #pragma unroll
            for (int j=0;j<8;++j) cv[j] = X[rr][tc*8+j];
            #pragma unroll
            for (int i=0;i<8;++i)
                #pragma unroll
                for (int j=0;j<8;++j) acc[i][j] += rv[i]*cv[j];
        }
        if (tid < CIN){
            #pragma unroll 4
            for (int rr = 0; rr < lim; ++rr) ps += X[rr][tid];
        }
    }
    for (int i=0;i<8;++i)
        for (int j=0;j<8;++j)
            atomicAdd(&G[(tr*8+i)*CIN + tc*8+j], acc[i][j]);
    if (tid < CIN) atomicAdd(&s[tid], ps);
}

// ---------- 64-wide Gram (chunked LDS), optional affine+leaky (bf16 out), optional weights ----------
__global__ __launch_bounds__(256) void gram64_kernel(const float* __restrict__ src,
                                                     const float* __restrict__ wts,
                                                     const float* __restrict__ ta,
                                                     const float* __restrict__ tcp,
                                                     ushort* __restrict__ outrow,
                                                     float* __restrict__ G, float* __restrict__ s, int N)
{
    __shared__ float X[G64_CHUNK][CH];     // 16 KB
    __shared__ float Wt[G64_CHUNK];
    int tid = threadIdx.x;
    int tr = tid >> 4, tcl = tid & 15;
    float acc[4][4] = {};
    float ps = 0.f;
    for (int base = blockIdx.x*G64_CHUNK; base < N; base += gridDim.x*G64_CHUNK){
        __syncthreads();
        for (int i = tid; i < G64_CHUNK*16; i += 256){
            int r = i >> 4, c4 = i & 15;
            int n = base + r;
            float4 v = make_float4(0.f,0.f,0.f,0.f);
            if (n < N){
                v = ((const float4*)src)[(size_t)n*16 + c4];
                if (ta){
                    float4 av = ((const float4*)ta)[c4];
                    float4 cv4 = ((const float4*)tcp)[c4];
                    v.x = leakyf(av.x*v.x + cv4.x);
                    v.y = leakyf(av.y*v.y + cv4.y);
                    v.z = leakyf(av.z*v.z + cv4.z);
                    v.w = leakyf(av.w*v.w + cv4.w);
                    if (outrow){
                        uint2 pk;
                        pk.x = (unsigned)f2bf(v.x) | ((unsigned)f2bf(v.y) << 16);
                        pk.y = (unsigned)f2bf(v.z) | ((unsigned)f2bf(v.w) << 16);
                        ((uint2*)outrow)[(size_t)n*16 + c4] = pk;
                    }
                }
            }
            X[r][c4*4+0]=v.x; X[r][c4*4+1]=v.y; X[r][c4*4+2]=v.z; X[r][c4*4+3]=v.w;
            if (c4 == 0) Wt[r] = (n < N) ? (wts ? wts[n] : 1.0f) : 0.0f;
        }
        __syncthreads();
        int lim = min(G64_CHUNK, N - base);
        #pragma unroll 4
        for (int rr = 0; rr < lim; ++rr){
            float w = Wt[rr];
            float rv[4], cv[4];
            #pragma unroll
            for (int i=0;i<4;++i) rv[i] = X[rr][tr*4+i]*w;
            #pragma unroll
            for (int j=0;j<4;++j) cv[j] = X[rr][tcl*4+j];
            #pragma unroll
            for (int i=0;i<4;++i)
                #pragma unroll
                for (int j=0;j<4;++j) acc[i][j] += rv[i]*cv[j];
        }
        if (tid < CH){
            #pragma unroll 4
            for (int rr = 0; rr < lim; ++rr) ps += Wt[rr]*X[rr][tid];
        }
    }
    for (int i=0;i<4;++i)
        for (int j=0;j<4;++j)
            atomicAdd(&G[(tr*4+i)*CH + tcl*4+j], acc[i][j]);
    if (tid < CH) atomicAdd(&s[tid], ps);
}

// ---------- derive BN affine (a,c) for y = X@W from Gram/colsum of X ----------
__global__ void finalize_lin_bn(const float* __restrict__ G, const float* __restrict__ s,
                                const float* __restrict__ W, const float* __restrict__ g,
                                const float* __restrict__ b, float invcnt, int D, int M,
                                float* __restrict__ a, float* __restrict__ c)
{
    int o = blockIdx.x, lane = threadIdx.x;   // 64 threads
    float pm = 0.f, pq = 0.f;
    for (int i = lane; i < D; i += 64){
        float wi = W[i*M + o];
        pm += s[i]*wi;
        float t = 0.f;
        for (int j = 0; j < D; ++j) t += G[i*D + j]*W[j*M + o];
        pq += wi*t;
    }
    #pragma unroll
    for (int off = 32; off; off >>= 1){
        pm += __shfl_down(pm, off);
        pq += __shfl_down(pq, off);
    }
    if (lane == 0){
        float m  = pm*invcnt;
        float E2 = pq*invcnt;
        float var = E2 - m*m;
        float ai = g[o]*rsqrtf(var + BN_EPS);
        a[o] = ai; c[o] = b[o] - m*ai;
    }
}

// ---------- derive BN affine from per-block partial (sum,sumsq) slabs ----------
__global__ __launch_bounds__(256) void finalize_direct(const float* __restrict__ part, int nrows,
                                                       const float* __restrict__ g, const float* __restrict__ b,
                                                       float invcnt, float* __restrict__ a, float* __restrict__ c)
{
    int tid = threadIdx.x; int t = tid & 63, seg = tid >> 6;
    float s = 0.f, ss = 0.f;
    for (int r = seg; r < nrows; r += 4){ s += part[r*128 + t]; ss += part[r*128 + 64 + t]; }
    __shared__ float r1[256], r2[256];
    r1[tid] = s; r2[tid] = ss;
    __syncthreads();
    if (tid < 64){
        s  = r1[tid] + r1[tid+64] + r1[tid+128] + r1[tid+192];
        ss = r2[tid] + r2[tid+64] + r2[tid+128] + r2[tid+192];
        float m = s*invcnt, var = ss*invcnt - m*m;
        float ai = g[tid]*rsqrtf(var + BN_EPS);
        a[tid] = ai; c[tid] = b[tid] - m*ai;
    }
}

// ---------- neighbor-index histogram ----------
__global__ void hist_kernel(const int* __restrict__ inds, int total, int N, float* __restrict__ cnt)
{
    int i = blockIdx.x*256 + threadIdx.x;
    if (i < total){
        int ix = inds[i];
        if ((unsigned)ix < (unsigned)N) atomicAdd(&cnt[ix], 1.0f);
    }
}

// ---------- fp32 -> bf16 bulk convert (x4 vectorized) ----------
__global__ void cvt_bf16x4_kernel(const float* __restrict__ src, ushort* __restrict__ dst, int total4)
{
    int i = blockIdx.x*256 + threadIdx.x;
    if (i < total4){
        float4 v = ((const float4*)src)[i];
        uint2 p;
        p.x = (unsigned)f2bf(v.x) | ((unsigned)f2bf(v.y) << 16);
        p.y = (unsigned)f2bf(v.z) | ((unsigned)f2bf(v.w) << 16);
        ((uint2*)dst)[i] = p;
    }
}

// ---------- x = leaky(a1*(feat@W)+c1): fp32 out + bf16 out ----------
__global__ __launch_bounds__(256) void unary1_gemm_kernel(const float* __restrict__ feat,
    const float* __restrict__ W, const float* __restrict__ a1, const float* __restrict__ c1,
    float* __restrict__ xout, ushort* __restrict__ xbf, int N)
{
    __shared__ float rows[64*129];
    __shared__ float wt[CIN*CH];
    int tid = threadIdx.x;
    for (int i = tid; i < CIN*CH; i += 256) wt[i] = a1[i & 63]*W[i];
    int nb = blockIdx.x*64;
    for (int i = tid; i < 2048; i += 256){
        int r = i >> 5, c4 = i & 31;
        int n = nb + r;
        float4 v = make_float4(0.f,0.f,0.f,0.f);
        if (n < N) v = ((const float4*)feat)[(size_t)n*32 + c4];
        rows[r*129 + c4*4+0]=v.x; rows[r*129 + c4*4+1]=v.y;
        rows[r*129 + c4*4+2]=v.z; rows[r*129 + c4*4+3]=v.w;
    }
    __syncthreads();
    int tn = tid & 15, to = tid >> 4;
    float acc[4][4] = {};
    for (int c = 0; c < CIN; ++c){
        float rv[4], wv[4];
        #pragma unroll
        for (int i=0;i<4;++i) rv[i] = rows[(tn*4+i)*129 + c];
        #pragma unroll
        for (int j=0;j<4;++j) wv[j] = wt[c*CH + to*4 + j];
        #pragma unroll
        for (int i=0;i<4;++i)
            #pragma unroll
            for (int j=0;j<4;++j) acc[i][j] += rv[i]*wv[j];
    }
    #pragma unroll
    for (int i=0;i<4;++i){
        int n = nb + tn*4 + i;
        if (n >= N) continue;
        #pragma unroll
        for (int j=0;j<4;++j){
            int o = to*4 + j;
            float v = leakyf(acc[i][j] + c1[o]);
            xout[(size_t)n*CH + o] = v;
            xbf[(size_t)n*CH + o] = f2bf(v);
        }
    }
}

// ---------- prep: W0T scaled by a0, bf16: w0t[d][c] = a0[d]*W0[c][d] ----------
__global__ void prep_w0_kernel(const float* __restrict__ W0, const float* __restrict__ a0,
                               ushort* __restrict__ w0t)
{
    int i = blockIdx.x*256 + threadIdx.x;
    if (i < CH*CH){ int d = i >> 6, c = i & 63; w0t[i] = f2bf(a0[d]*W0[c*CH + d]); }
}

// ---------- prep: w1s[(c*64+h)][dd] = W1[dd][3h+c], bf16 ----------
__global__ void prep_w1_kernel(const float* __restrict__ W1, ushort* __restrict__ w1s)
{
    int i = blockIdx.x*256 + threadIdx.x;
    if (i < 192*CH){
        int r = i >> 6, dd = i & 63;
        int c = r >> 6, h = r & 63;
        w1s[i] = f2bf(W1[dd*192 + 3*h + c]);
    }
}

// ---------- prep: wcat[o][kk] = scaled concat(Wsc,Wu2)^T bf16 ; ccomb = csc+c2o ----------
__global__ void prep_final_kernel(const float* __restrict__ Wsc, const float* __restrict__ Wu2,
    const float* __restrict__ asc, const float* __restrict__ csc,
    const float* __restrict__ a2o, const float* __restrict__ c2o,
    ushort* __restrict__ wcat, float* __restrict__ ccomb)
{
    int i = blockIdx.x*256 + threadIdx.x;
    if (i < COUT*192){
        int o = i / 192, kk = i % 192;
        float v = (kk < CIN) ? asc[o]*Wsc[kk*COUT + o] : a2o[o]*Wu2[(kk-CIN)*COUT + o];
        wcat[i] = f2bf(v);
    }
    if (i < COUT) ccomb[i] = csc[i] + c2o[i];
}

// ---------- fused MFMA: gather -> conv0(swapped) -> bn0+leaky -> nbx-scaled k0c -> conv1 -> stats ----------
__global__ __launch_bounds__(512) void conv_msg_mfma(
    const ushort* __restrict__ xbf, const float* __restrict__ qp, const float* __restrict__ sp,
    const int* __restrict__ inds, const ushort* __restrict__ w0t, const ushort* __restrict__ w1s,
    const float* __restrict__ c0p,
    float* __restrict__ mx, float* __restrict__ mn, float* __restrict__ msgpart, int N)
{
    __shared__ unsigned char SM[24576 + 8*12288];   // Wstage (swizzled) + per-wave k0c tiles
    int tid = threadIdx.x;
    int warp = tid >> 6, lane = tid & 63;
    int l15 = lane & 15, g = lane >> 4;
    // stage w1s (192x64 bf16) into LDS, XOR-swizzled by row&7
    for (int ch = tid; ch < 1536; ch += 512){
        int r = ch >> 3, c16 = ch & 7;
        uint4 v = ((const uint4*)w1s)[ch];
        *(uint4*)(SM + r*128 + ((c16*16) ^ ((r&7)<<4))) = v;
    }
    // loop-invariant W0T fragments + c0
    bf16x8 wf[8];
    #pragma unroll
    for (int mt=0;mt<4;++mt)
        #pragma unroll
        for (int s=0;s<2;++s)
            wf[mt*2+s] = *(const bf16x8*)(w0t + (mt*16+l15)*CH + s*32 + g*8);
    float c0r[16];
    #pragma unroll
    for (int mt=0;mt<4;++mt)
        #pragma unroll
        for (int q=0;q<4;++q)
            c0r[mt*4+q] = c0p[mt*16 + g*4 + q];
    unsigned char* k0base = SM + 24576 + warp*12288;
    unsigned swz = (unsigned)((l15 & 7) << 4);
    float ps[4] = {0,0,0,0}, pss[4] = {0,0,0,0};
    const int nwaves = gridDim.x*8;
    const f32x4 z4 = {0.f,0.f,0.f,0.f};
    __syncthreads();

    for (int n = blockIdx.x*8 + warp; n < N; n += nwaves){
        int ix0 = inds[n*KNB + l15];
        int ix1 = inds[n*KNB + 16 + l15];
        if ((unsigned)ix0 > (unsigned)N) ix0 = N;
        if ((unsigned)ix1 > (unsigned)N) ix1 = N;
        float qx = qp[n*3+0], qy = qp[n*3+1], qz = qp[n*3+2];
        float nbv[2][3];
        if (ix0 < N){ nbv[0][0]=sp[ix0*3]-qx; nbv[0][1]=sp[ix0*3+1]-qy; nbv[0][2]=sp[ix0*3+2]-qz; }
        else        { nbv[0][0]=-qx; nbv[0][1]=-qy; nbv[0][2]=-qz; }
        if (ix1 < N){ nbv[1][0]=sp[ix1*3]-qx; nbv[1][1]=sp[ix1*3+1]-qy; nbv[1][2]=sp[ix1*3+2]-qz; }
        else        { nbv[1][0]=-qx; nbv[1][1]=-qy; nbv[1][2]=-qz; }
        // gather nb_y fragments (B operand of swapped conv0), 16B per lane
        bf16x8 xf0a = *(const bf16x8*)(xbf + (size_t)ix0*CH +      g*8);
        bf16x8 xf0b = *(const bf16x8*)(xbf + (size_t)ix0*CH + 32 + g*8);
        bf16x8 xf1a = *(const bf16x8*)(xbf + (size_t)ix1*CH +      g*8);
        bf16x8 xf1b = *(const bf16x8*)(xbf + (size_t)ix1*CH + 32 + g*8);
        // conv0: z0^T = (a0.W0^T) @ nb_y^T   (M=d:4 tiles, N=k:2 tiles, K=c:2 steps)
        f32x4 acc0[8];
        #pragma unroll
        for (int i=0;i<8;++i) acc0[i] = z4;
        #pragma unroll
        for (int mt=0;mt<4;++mt){
            acc0[mt*2+0] = __builtin_amdgcn_mfma_f32_16x16x32_bf16(wf[mt*2+0], xf0a, acc0[mt*2+0], 0,0,0);
            acc0[mt*2+0] = __builtin_amdgcn_mfma_f32_16x16x32_bf16(wf[mt*2+1], xf0b, acc0[mt*2+0], 0,0,0);
            acc0[mt*2+1] = __builtin_amdgcn_mfma_f32_16x16x32_bf16(wf[mt*2+0], xf1a, acc0[mt*2+1], 0,0,0);
            acc0[mt*2+1] = __builtin_amdgcn_mfma_f32_16x16x32_bf16(wf[mt*2+1], xf1b, acc0[mt*2+1], 0,0,0);
        }
        // bn0 (+c0) + leaky, scale by nbx[c], pack bf16, write k0c[c][k][d] (swizzled)
        #pragma unroll
        for (int mt=0;mt<4;++mt){
            #pragma unroll
            for (int ntk=0;ntk<2;++ntk){
                f32x4 a = acc0[mt*2+ntk];
                float v0 = leakyf(a[0] + c0r[mt*4+0]);
                float v1 = leakyf(a[1] + c0r[mt*4+1]);
                float v2 = leakyf(a[2] + c0r[mt*4+2]);
                float v3 = leakyf(a[3] + c0r[mt*4+3]);
                #pragma unroll
                for (int c=0;c<3;++c){
                    float w = nbv[ntk][c];
                    uint2 pk;
                    pk.x = cvtpk(v0*w, v1*w);
                    pk.y = cvtpk(v2*w, v3*w);
                    *(uint2*)(k0base + (c*32 + ntk*16 + l15)*128 + ((unsigned)(mt*32 + g*8) ^ swz)) = pk;
                }
            }
        }
        // conv1: msg = sum_c (k0*nbx_c) @ W1_c   (M=k:2 tiles, N=h:4 tiles, K=dd:2 steps, c:3)
        f32x4 acc1[8];
        #pragma unroll
        for (int i=0;i<8;++i) acc1[i] = z4;
        #pragma unroll
        for (int c=0;c<3;++c){
            #pragma unroll
            for (int ks=0;ks<2;++ks){
                unsigned co = ((unsigned)(ks*64 + g*16)) ^ swz;
                bf16x8 a0f = *(const bf16x8*)(k0base + (c*32 +      l15)*128 + co);
                bf16x8 a1f = *(const bf16x8*)(k0base + (c*32 + 16 + l15)*128 + co);
                #pragma unroll
                for (int nt=0;nt<4;++nt){
                    bf16x8 bfr = *(const bf16x8*)(SM + (c*64 + nt*16 + l15)*128 + co);
                    acc1[0*4+nt] = __builtin_amdgcn_mfma_f32_16x16x32_bf16(a0f, bfr, acc1[0*4+nt], 0,0,0);
                    acc1[1*4+nt] = __builtin_amdgcn_mfma_f32_16x16x32_bf16(a1f, bfr, acc1[1*4+nt], 0,0,0);
                }
            }
        }
        // reduce over k: per-lane 8 vals, then butterfly over lane>>4 groups
        #pragma unroll
        for (int nt=0;nt<4;++nt){
            float vmx = -3.4e38f, vmn = 3.4e38f, s = 0.f, ssq = 0.f;
            #pragma unroll
            for (int mtk=0;mtk<2;++mtk){
                f32x4 a = acc1[mtk*4+nt];
                #pragma unroll
                for (int q=0;q<4;++q){
                    float v = a[q];
                    vmx = fmaxf(vmx, v); vmn = fminf(vmn, v);
                    s += v; ssq += v*v;
                }
            }
            vmx = fmaxf(vmx, __shfl_xor(vmx, 16)); vmn = fminf(vmn, __shfl_xor(vmn, 16));
            s  += __shfl_xor(s, 16);               ssq += __shfl_xor(ssq, 16);
            vmx = fmaxf(vmx, __shfl_xor(vmx, 32)); vmn = fminf(vmn, __shfl_xor(vmn, 32));
            s  += __shfl_xor(s, 32);               ssq += __shfl_xor(ssq, 32);
            if (lane < 16){
                mx[(size_t)n*CH + nt*16 + l15] = vmx;
                mn[(size_t)n*CH + nt*16 + l15] = vmn;
                ps[nt] += s; pss[nt] += ssq;
            }
        }
    }
    // block-level stat reduction (reuse LDS)
    __syncthreads();
    float* red = (float*)SM;
    if (lane < 16){
        #pragma unroll
        for (int nt=0;nt<4;++nt){
            red[warp*128 + nt*16 + l15]        = ps[nt];
            red[1024 + warp*128 + nt*16 + l15] = pss[nt];
        }
    }
    __syncthreads();
    if (tid < 64){
        float s = 0.f, ssq = 0.f;
        #pragma unroll
        for (int w8=0;w8<8;++w8){ s += red[w8*128 + tid]; ssq += red[1024 + w8*128 + tid]; }
        msgpart[(size_t)blockIdx.x*128 + tid]      = s;
        msgpart[(size_t)blockIdx.x*128 + 64 + tid] = ssq;
    }
}

// ---------- agg = leaky(a1m*(max or min)+c1m) ; bnc stat partials ----------
__global__ __launch_bounds__(256) void msg_agg_kernel(const float* __restrict__ mx, const float* __restrict__ mn,
    const float* __restrict__ a1m, const float* __restrict__ c1m,
    float* __restrict__ agg, float* __restrict__ aggpart, int total)
{
    int tid = threadIdx.x; int h = tid & 63;
    float ah = a1m[h], ch = c1m[h];
    bool useMax = (ah >= 0.f);
    float ps = 0.f, pss = 0.f;
    for (int i = blockIdx.x*256 + tid; i < total; i += gridDim.x*256){
        float sel = useMax ? mx[i] : mn[i];
        float v = leakyf(ah*sel + ch);
        agg[i] = v; ps += v; pss += v*v;
    }
    __shared__ float r1[256], r2[256];
    r1[tid] = ps; r2[tid] = pss;
    __syncthreads();
    if (tid < 64){
        float s  = r1[tid] + r1[tid+64] + r1[tid+128] + r1[tid+192];
        float ss = r2[tid] + r2[tid+64] + r2[tid+128] + r2[tid+192];
        aggpart[(size_t)blockIdx.x*128 + tid]      = s;
        aggpart[(size_t)blockIdx.x*128 + 64 + tid] = ss;
    }
}

// ---------- final: out = leaky( [featbf|a2b2] @ wcat^T + ccomb ), bf16 MFMA ----------
__global__ __launch_bounds__(256) void final_mfma_kernel(
    const ushort* __restrict__ featbf, const ushort* __restrict__ a2b2,
    const ushort* __restrict__ wcat, const float* __restrict__ ccomb,
    float* __restrict__ out, int N)
{
    int tid = threadIdx.x, warp = tid >> 6, lane = tid & 63;
    int l15 = lane & 15, g = lane >> 4;
    int row0 = blockIdx.x*64 + warp*16;
    const f32x4 z4 = {0.f,0.f,0.f,0.f};
    f32x4 acc[16];
    #pragma unroll
    for (int i=0;i<16;++i) acc[i] = z4;
    int r = row0 + l15;
    bool ok = r < N;
    #pragma unroll
    for (int s=0;s<6;++s){
        bf16x8 af = {0,0,0,0,0,0,0,0};
        if (ok){
            const ushort* srcp = (s < 4) ? (featbf + (size_t)r*CIN + s*32 + g*8)
                                         : (a2b2  + (size_t)r*CH + (s-4)*32 + g*8);
            af = *(const bf16x8*)srcp;
        }
        #pragma unroll
        for (int nt=0;nt<16;++nt){
            bf16x8 bfr = *(const bf16x8*)(wcat + (nt*16+l15)*192 + s*32 + g*8);
            acc[nt] = __builtin_amdgcn_mfma_f32_16x16x32_bf16(af, bfr, acc[nt], 0,0,0);
        }
    }
    #pragma unroll
    for (int nt=0;nt<16;++nt){
        float cc = ccomb[nt*16 + l15];
        #pragma unroll
        for (int q=0;q<4;++q){
            int rr = row0 + g*4 + q;
            if (rr < N){
                float v = acc[nt][q] + cc;
                out[(size_t)rr*COUT + nt*16 + l15] = leakyf(v);
            }
        }
    }
}

extern "C" void kernel_launch(void* const* d_in, const int* in_sizes, int n_in,
                              void* d_out, int out_size, void* d_ws, size_t ws_size,
                              hipStream_t stream)
{
    const float* feat = (const float*)d_in[0];
    const float* qp   = (const float*)d_in[1];
    const float* sp   = (const float*)d_in[2];
    const int*   inds = (const int*)d_in[3];
    const float* Wu1  = (const float*)d_in[4];
    const float* g1   = (const float*)d_in[5];
    const float* b1   = (const float*)d_in[6];
    const float* W0   = (const float*)d_in[7];
    const float* gb0  = (const float*)d_in[8];
    const float* bb0  = (const float*)d_in[9];
    const float* W1   = (const float*)d_in[10];
    const float* gb1  = (const float*)d_in[11];
    const float* bb1  = (const float*)d_in[12];
    const float* gbc  = (const float*)d_in[13];
    const float* bbc  = (const float*)d_in[14];
    const float* Wu2  = (const float*)d_in[15];
    const float* g2   = (const float*)d_in[16];
    const float* b2   = (const float*)d_in[17];
    const float* Wsc  = (const float*)d_in[18];
    const float* gsc  = (const float*)d_in[19];
    const float* bsc  = (const float*)d_in[20];

    const int N = in_sizes[0] / CIN;           // 20000

    float* ws   = (float*)d_ws;
    float* XtX  = ws;                              // 16384
    float* fsum = XtX + 16384;                     // 128
    float* G0   = fsum + 128;                      // 4096
    float* s0   = G0 + 4096;                       // 64
    float* G2   = s0 + 64;                         // 4096
    float* s2   = G2 + 4096;                       // 64
    float* cnt  = s2 + 64;                         // N
    float* prm  = cnt + N;                         // 1536 params
    float* a1 = prm,      *c1 = prm+64,  *a0 = prm+128,  *c0 = prm+192;
    float* a1m = prm+256, *c1m = prm+320, *abnc = prm+384, *cbnc = prm+448;
    float* asc = prm+512, *csc = prm+768, *a2o = prm+1024, *c2o = prm+1280;
    float* msgpart = prm + 1536;                   // CONV_GRID*128
    float* aggpart = msgpart + CONV_GRID*128;      // AGG_GRID*128
    float* xbuf = aggpart + AGG_GRID*128;          // N*64 f32
    float* mxb  = xbuf + (size_t)N*CH;             // N*64
    float* mnb  = mxb  + (size_t)N*CH;             // N*64
    float* aggb = mnb  + (size_t)N*CH;             // N*64
    float* p    = aggb + (size_t)N*CH;
    ushort* xbf    = (ushort*)p;  p += (size_t)(N+1)*CH/2;   // (N+1)*64 bf16
    ushort* featbf = (ushort*)p;  p += (size_t)N*CIN/2;      // N*128 bf16
    ushort* a2b2   = (ushort*)p;  p += (size_t)N*CH/2;       // N*64 bf16
    ushort* w0t    = (ushort*)p;  p += 2048;                 // 64*64 bf16
    ushort* w1s    = (ushort*)p;  p += 6144;                 // 192*64 bf16
    ushort* wcat   = (ushort*)p;  p += 24576;                // 256*192 bf16
    float*  ccomb  = p;                                      // 256 f32

    size_t statsBytes = (size_t)(16384 + 128 + 4096 + 64 + 4096 + 64 + N) * sizeof(float);
    hipMemsetAsync(d_ws, 0, statsBytes, stream);
    hipMemsetAsync((void*)(xbf + (size_t)N*CH), 0, CH*sizeof(ushort), stream);  // zero shadow row

    const int nTiles = (N + 63) / 64;

    cvt_bf16x4_kernel<<<(N*CIN/4 + 255)/256, 256, 0, stream>>>(feat, featbf, N*CIN/4);
    prep_w1_kernel<<<48, 256, 0, stream>>>(W1, w1s);
    gram128_kernel<<<G128_GRID, 256, 0, stream>>>(feat, N, XtX, fsum);
    finalize_lin_bn<<<CH, 64, 0, stream>>>(XtX, fsum, Wu1, g1, b1, 1.0f/N, CIN, CH, a1, c1);
    finalize_lin_bn<<<COUT, 64, 0, stream>>>(XtX, fsum, Wsc, gsc, bsc, 1.0f/N, CIN, COUT, asc, csc);
    unary1_gemm_kernel<<<nTiles, 256, 0, stream>>>(feat, Wu1, a1, c1, xbuf, xbf, N);
    hist_kernel<<<(N*KNB + 255)/256, 256, 0, stream>>>(inds, N*KNB, N, cnt);
    gram64_kernel<<<G64_GRID, 256, 0, stream>>>(xbuf, cnt, nullptr, nullptr, nullptr, G0, s0, N);
    finalize_lin_bn<<<CH, 64, 0, stream>>>(G0, s0, W0, gb0, bb0, 1.0f/((float)N*KNB), CH, CH, a0, c0);
    prep_w0_kernel<<<16, 256, 0, stream>>>(W0, a0, w0t);
    conv_msg_mfma<<<CONV_GRID, 512, 0, stream>>>(xbf, qp, sp, inds, w0t, w1s, c0, mxb, mnb, msgpart, N);
    finalize_direct<<<1, 256, 0, stream>>>(msgpart, CONV_GRID, gb1, bb1, 1.0f/((float)N*KNB), a1m, c1m);
    msg_agg_kernel<<<AGG_GRID, 256, 0, stream>>>(mxb, mnb, a1m, c1m, aggb, aggpart, N*CH);
    finalize_direct<<<1, 256, 0, stream>>>(aggpart, AGG_GRID, gbc, bbc, 1.0f/N, abnc, cbnc);
    gram64_kernel<<<G64_GRID, 256, 0, stream>>>(aggb, nullptr, abnc, cbnc, a2b2, G2, s2, N);
    finalize_lin_bn<<<COUT, 64, 0, stream>>>(G2, s2, Wu2, g2, b2, 1.0f/N, CH, COUT, a2o, c2o);
    prep_final_kernel<<<192, 256, 0, stream>>>(Wsc, Wu2, asc, csc, a2o, c2o, wcat, ccomb);
    final_mfma_kernel<<<(N+63)/64, 256, 0, stream>>>(featbf, a2b2, wcat, ccomb, (float*)d_out, N);
}

// Round 4
// 337.067 us; speedup vs baseline: 4.4355x; 1.3514x over previous
//
#include <hip/hip_runtime.h>

#define KNB 32
#define CIN 128
#define CH 64
#define COUT 256
#define BN_EPS 1e-5f
#define CONV_GRID 256
#define AGG_GRID 256
#define G128_GRID 128
#define G64_GRID 128

typedef __attribute__((ext_vector_type(8))) short bf16x8;
typedef __attribute__((ext_vector_type(4))) float f32x4;

static __device__ __forceinline__ float leakyf(float v){ return fmaxf(v, 0.1f*v); }

static __device__ __forceinline__ unsigned short f2bf(float f){
    unsigned u = __float_as_uint(f);
    u += 0x7FFFu + ((u >> 16) & 1u);
    return (unsigned short)(u >> 16);
}
static __device__ __forceinline__ float bf2f(ushort u){ return __uint_as_float(((unsigned)u) << 16); }

static __device__ __forceinline__ unsigned cvtpk(float lo, float hi){
    unsigned r;
    asm("v_cvt_pk_bf16_f32 %0, %1, %2" : "=v"(r) : "v"(lo), "v"(hi));
    return r;
}

// ---------- MFMA Gram of featbf: partial G[128][128] + colsum[128] per block ----------
__global__ __launch_bounds__(256) void gram128_mfma(const ushort* __restrict__ xb, int N,
                                                    float* __restrict__ slab)
{
    __shared__ ushort Xt[128][40];      // transposed chunk (32 rows), +8 pad
    __shared__ float red[16][128];
    int tid = threadIdx.x;
    int wave = tid >> 6, lane = tid & 63, l15 = lane & 15, g = lane >> 4;
    int Mq = wave >> 1, Nq = wave & 1;
    const f32x4 z4 = {0.f,0.f,0.f,0.f};
    f32x4 acc[4][4];
    #pragma unroll
    for (int i=0;i<4;++i)
        #pragma unroll
        for (int j=0;j<4;++j) acc[i][j] = z4;
    float pcs[8] = {0,0,0,0,0,0,0,0};
    int nch = (N + 31) >> 5;
    for (int ch = blockIdx.x; ch < nch; ch += gridDim.x){
        int base = ch << 5;
        __syncthreads();
        #pragma unroll
        for (int ii = 0; ii < 2; ++ii){
            int i = tid + ii*256;
            int r = i >> 4, cq = i & 15;
            int n = base + r;
            uint4 v = make_uint4(0,0,0,0);
            if (n < N) v = ((const uint4*)xb)[(size_t)n*16 + cq];
            ushort us[8] = {(ushort)(v.x&0xffff),(ushort)(v.x>>16),(ushort)(v.y&0xffff),(ushort)(v.y>>16),
                            (ushort)(v.z&0xffff),(ushort)(v.z>>16),(ushort)(v.w&0xffff),(ushort)(v.w>>16)};
            #pragma unroll
            for (int j=0;j<8;++j){
                Xt[cq*8+j][r] = us[j];
                pcs[j] += bf2f(us[j]);
            }
        }
        __syncthreads();
        bf16x8 af[4], bv[4];
        #pragma unroll
        for (int t=0;t<4;++t){
            af[t] = *(const bf16x8*)&Xt[Mq*64 + t*16 + l15][g*8];
            bv[t] = *(const bf16x8*)&Xt[Nq*64 + t*16 + l15][g*8];
        }
        #pragma unroll
        for (int mi=0;mi<4;++mi)
            #pragma unroll
            for (int ni=0;ni<4;++ni)
                acc[mi][ni] = __builtin_amdgcn_mfma_f32_16x16x32_bf16(af[mi], bv[ni], acc[mi][ni], 0,0,0);
    }
    float* Gp = slab + (size_t)blockIdx.x*16512;
    #pragma unroll
    for (int mi=0;mi<4;++mi)
        #pragma unroll
        for (int ni=0;ni<4;++ni)
            #pragma unroll
            for (int q=0;q<4;++q)
                Gp[(Mq*64+mi*16+g*4+q)*CIN + Nq*64+ni*16+l15] = acc[mi][ni][q];
    __syncthreads();
    #pragma unroll
    for (int j=0;j<8;++j) red[tid>>4][(tid&15)*8+j] = pcs[j];
    __syncthreads();
    if (tid < CIN){
        float s = 0.f;
        #pragma unroll
        for (int grp=0;grp<16;++grp) s += red[grp][tid];
        Gp[16384 + tid] = s;
    }
}

// ---------- MFMA weighted Gram of xbf (weights cnt): partial G0[64][64] + wcolsum ----------
__global__ __launch_bounds__(256) void gram64w_mfma(const ushort* __restrict__ xb,
    const float* __restrict__ wts, int N, float* __restrict__ slab)
{
    __shared__ ushort XtA[64][72];   // weighted (A side)
    __shared__ ushort XtB[64][72];
    __shared__ float red[32][64];
    int tid = threadIdx.x;
    int wave = tid >> 6, lane = tid & 63, l15 = lane & 15, g = lane >> 4;
    int Mq = wave >> 1, Nq = wave & 1;
    const f32x4 z4 = {0.f,0.f,0.f,0.f};
    f32x4 acc[2][2];
    #pragma unroll
    for (int i=0;i<2;++i){ acc[i][0] = z4; acc[i][1] = z4; }
    float pcs[8] = {0,0,0,0,0,0,0,0};
    int nch = (N + 63) >> 6;
    for (int ch = blockIdx.x; ch < nch; ch += gridDim.x){
        int base = ch << 6;
        __syncthreads();
        #pragma unroll
        for (int ii = 0; ii < 2; ++ii){
            int i = tid + ii*256;
            int r = i >> 3, cq = i & 7;
            int n = base + r;
            uint4 v = make_uint4(0,0,0,0);
            float w = 0.f;
            if (n < N){ v = ((const uint4*)xb)[(size_t)n*8 + cq]; w = wts[n]; }
            ushort us[8] = {(ushort)(v.x&0xffff),(ushort)(v.x>>16),(ushort)(v.y&0xffff),(ushort)(v.y>>16),
                            (ushort)(v.z&0xffff),(ushort)(v.z>>16),(ushort)(v.w&0xffff),(ushort)(v.w>>16)};
            #pragma unroll
            for (int j=0;j<8;++j){
                float f = bf2f(us[j]);
                XtB[cq*8+j][r] = us[j];
                XtA[cq*8+j][r] = f2bf(w*f);
                pcs[j] += w*f;
            }
        }
        __syncthreads();
        #pragma unroll
        for (int ks=0;ks<2;++ks){
            bf16x8 af[2], bv[2];
            #pragma unroll
            for (int t=0;t<2;++t){
                af[t] = *(const bf16x8*)&XtA[Mq*32 + t*16 + l15][ks*32 + g*8];
                bv[t] = *(const bf16x8*)&XtB[Nq*32 + t*16 + l15][ks*32 + g*8];
            }
            #pragma unroll
            for (int mi=0;mi<2;++mi)
                #pragma unroll
                for (int ni=0;ni<2;++ni)
                    acc[mi][ni] = __builtin_amdgcn_mfma_f32_16x16x32_bf16(af[mi], bv[ni], acc[mi][ni], 0,0,0);
        }
    }
    float* Gp = slab + (size_t)blockIdx.x*4160;
    #pragma unroll
    for (int mi=0;mi<2;++mi)
        #pragma unroll
        for (int ni=0;ni<2;++ni)
            #pragma unroll
            for (int q=0;q<4;++q)
                Gp[(Mq*32+mi*16+g*4+q)*CH + Nq*32+ni*16+l15] = acc[mi][ni][q];
    __syncthreads();
    #pragma unroll
    for (int j=0;j<8;++j) red[tid>>3][(tid&7)*8+j] = pcs[j];
    __syncthreads();
    if (tid < CH){
        float s = 0.f;
        #pragma unroll
        for (int grp=0;grp<32;++grp) s += red[grp][tid];
        Gp[4096 + tid] = s;
    }
}

// ---------- MFMA Gram with affine+leaky transform: aggb -> a2b2(bf16) + partial G2 + colsum ----------
__global__ __launch_bounds__(256) void gram64t_mfma(const float* __restrict__ src,
    const float* __restrict__ ta, const float* __restrict__ tcp,
    ushort* __restrict__ outrow, int N, float* __restrict__ slab)
{
    __shared__ ushort Xt[64][72];
    __shared__ float red[16][64];
    int tid = threadIdx.x;
    int wave = tid >> 6, lane = tid & 63, l15 = lane & 15, g = lane >> 4;
    int Mq = wave >> 1, Nq = wave & 1;
    const f32x4 z4 = {0.f,0.f,0.f,0.f};
    f32x4 acc[2][2];
    #pragma unroll
    for (int i=0;i<2;++i){ acc[i][0] = z4; acc[i][1] = z4; }
    float pcs[4] = {0,0,0,0};
    int nch = (N + 63) >> 6;
    for (int ch = blockIdx.x; ch < nch; ch += gridDim.x){
        int base = ch << 6;
        __syncthreads();
        #pragma unroll
        for (int ii = 0; ii < 4; ++ii){
            int i = tid + ii*256;
            int r = i >> 4, cq = i & 15;
            int n = base + r;
            float4 v = make_float4(0.f,0.f,0.f,0.f);
            if (n < N){
                v = ((const float4*)src)[(size_t)n*16 + cq];
                float4 av = ((const float4*)ta)[cq];
                float4 cv = ((const float4*)tcp)[cq];
                v.x = leakyf(av.x*v.x + cv.x);
                v.y = leakyf(av.y*v.y + cv.y);
                v.z = leakyf(av.z*v.z + cv.z);
                v.w = leakyf(av.w*v.w + cv.w);
                uint2 pk;
                pk.x = cvtpk(v.x, v.y);
                pk.y = cvtpk(v.z, v.w);
                ((uint2*)outrow)[(size_t)n*16 + cq] = pk;
            }
            Xt[cq*4+0][r] = f2bf(v.x);
            Xt[cq*4+1][r] = f2bf(v.y);
            Xt[cq*4+2][r] = f2bf(v.z);
            Xt[cq*4+3][r] = f2bf(v.w);
            pcs[0] += v.x; pcs[1] += v.y; pcs[2] += v.z; pcs[3] += v.w;
        }
        __syncthreads();
        #pragma unroll
        for (int ks=0;ks<2;++ks){
            bf16x8 af[2], bv[2];
            #pragma unroll
            for (int t=0;t<2;++t){
                af[t] = *(const bf16x8*)&Xt[Mq*32 + t*16 + l15][ks*32 + g*8];
                bv[t] = *(const bf16x8*)&Xt[Nq*32 + t*16 + l15][ks*32 + g*8];
            }
            #pragma unroll
            for (int mi=0;mi<2;++mi)
                #pragma unroll
                for (int ni=0;ni<2;++ni)
                    acc[mi][ni] = __builtin_amdgcn_mfma_f32_16x16x32_bf16(af[mi], bv[ni], acc[mi][ni], 0,0,0);
        }
    }
    float* Gp = slab + (size_t)blockIdx.x*4160;
    #pragma unroll
    for (int mi=0;mi<2;++mi)
        #pragma unroll
        for (int ni=0;ni<2;++ni)
            #pragma unroll
            for (int q=0;q<4;++q)
                Gp[(Mq*32+mi*16+g*4+q)*CH + Nq*32+ni*16+l15] = acc[mi][ni][q];
    __syncthreads();
    #pragma unroll
    for (int j=0;j<4;++j) red[tid>>4][(tid&15)*4+j] = pcs[j];
    __syncthreads();
    if (tid < CH){
        float s = 0.f;
        #pragma unroll
        for (int grp=0;grp<16;++grp) s += red[grp][tid];
        Gp[4096 + tid] = s;
    }
}

// ---------- sum per-block partial slabs -> dst (coalesced, no atomics) ----------
__global__ __launch_bounds__(256) void reduce_slab(const float* __restrict__ slab, int nparts, int len,
                                                   float* __restrict__ dst)
{
    int j = blockIdx.x*256 + threadIdx.x;
    if (j < len){
        float s0 = 0.f, s1 = 0.f, s2 = 0.f, s3 = 0.f;
        int b = 0;
        for (; b + 4 <= nparts; b += 4){
            s0 += slab[(size_t)(b+0)*len + j];
            s1 += slab[(size_t)(b+1)*len + j];
            s2 += slab[(size_t)(b+2)*len + j];
            s3 += slab[(size_t)(b+3)*len + j];
        }
        for (; b < nparts; ++b) s0 += slab[(size_t)b*len + j];
        dst[j] = (s0 + s1) + (s2 + s3);
    }
}

// ---------- derive BN affine (a,c) for y = X@W from Gram/colsum of X ----------
__global__ void finalize_lin_bn(const float* __restrict__ G, const float* __restrict__ s,
                                const float* __restrict__ W, const float* __restrict__ g,
                                const float* __restrict__ b, float invcnt, int D, int M,
                                float* __restrict__ a, float* __restrict__ c)
{
    int o = blockIdx.x, lane = threadIdx.x;   // 64 threads
    float pm = 0.f, pq = 0.f;
    for (int i = lane; i < D; i += 64){
        float wi = W[i*M + o];
        pm += s[i]*wi;
        float t = 0.f;
        for (int j = 0; j < D; ++j) t += G[i*D + j]*W[j*M + o];
        pq += wi*t;
    }
    #pragma unroll
    for (int off = 32; off; off >>= 1){
        pm += __shfl_down(pm, off);
        pq += __shfl_down(pq, off);
    }
    if (lane == 0){
        float m  = pm*invcnt;
        float E2 = pq*invcnt;
        float var = E2 - m*m;
        float ai = g[o]*rsqrtf(var + BN_EPS);
        a[o] = ai; c[o] = b[o] - m*ai;
    }
}

// ---------- derive BN affine from per-block partial (sum,sumsq) slabs ----------
__global__ __launch_bounds__(256) void finalize_direct(const float* __restrict__ part, int nrows,
                                                       const float* __restrict__ g, const float* __restrict__ b,
                                                       float invcnt, float* __restrict__ a, float* __restrict__ c)
{
    int tid = threadIdx.x; int t = tid & 63, seg = tid >> 6;
    float s = 0.f, ss = 0.f;
    for (int r = seg; r < nrows; r += 4){ s += part[r*128 + t]; ss += part[r*128 + 64 + t]; }
    __shared__ float r1[256], r2[256];
    r1[tid] = s; r2[tid] = ss;
    __syncthreads();
    if (tid < 64){
        s  = r1[tid] + r1[tid+64] + r1[tid+128] + r1[tid+192];
        ss = r2[tid] + r2[tid+64] + r2[tid+128] + r2[tid+192];
        float m = s*invcnt, var = ss*invcnt - m*m;
        float ai = g[tid]*rsqrtf(var + BN_EPS);
        a[tid] = ai; c[tid] = b[tid] - m*ai;
    }
}

// ---------- neighbor-index histogram ----------
__global__ void hist_kernel(const int* __restrict__ inds, int total, int N, float* __restrict__ cnt)
{
    int i = blockIdx.x*256 + threadIdx.x;
    if (i < total){
        int ix = inds[i];
        if ((unsigned)ix < (unsigned)N) atomicAdd(&cnt[ix], 1.0f);
    }
}

// ---------- fp32 -> bf16 bulk convert (x4 vectorized) ----------
__global__ void cvt_bf16x4_kernel(const float* __restrict__ src, ushort* __restrict__ dst, int total4)
{
    int i = blockIdx.x*256 + threadIdx.x;
    if (i < total4){
        float4 v = ((const float4*)src)[i];
        uint2 p;
        p.x = (unsigned)f2bf(v.x) | ((unsigned)f2bf(v.y) << 16);
        p.y = (unsigned)f2bf(v.z) | ((unsigned)f2bf(v.w) << 16);
        ((uint2*)dst)[i] = p;
    }
}

// ---------- prep: w1t[o][k] = a1[o]*Wu1[k][o], bf16 ----------
__global__ void prep_u1_kernel(const float* __restrict__ Wu1, const float* __restrict__ a1,
                               ushort* __restrict__ w1t)
{
    int i = blockIdx.x*256 + threadIdx.x;
    if (i < CH*CIN){ int o = i >> 7, k = i & 127; w1t[i] = f2bf(a1[o]*Wu1[k*CH + o]); }
}

// ---------- unary1 via MFMA: xbf = bf16(leaky(featbf @ w1t^T + c1)) ----------
__global__ __launch_bounds__(256) void unary1_mfma(const ushort* __restrict__ featbf,
    const ushort* __restrict__ w1t, const float* __restrict__ c1,
    ushort* __restrict__ xbf, int N)
{
    int tid = threadIdx.x, wave = tid >> 6, lane = tid & 63;
    int l15 = lane & 15, g = lane >> 4;
    int row0 = blockIdx.x*64 + wave*16;
    const f32x4 z4 = {0.f,0.f,0.f,0.f};
    f32x4 acc[4] = {z4, z4, z4, z4};
    int r = row0 + l15;
    bool ok = r < N;
    #pragma unroll
    for (int s=0;s<4;++s){
        bf16x8 af = {0,0,0,0,0,0,0,0};
        if (ok) af = *(const bf16x8*)(featbf + (size_t)r*CIN + s*32 + g*8);
        #pragma unroll
        for (int nt=0;nt<4;++nt){
            bf16x8 bfr = *(const bf16x8*)(w1t + (size_t)(nt*16+l15)*CIN + s*32 + g*8);
            acc[nt] = __builtin_amdgcn_mfma_f32_16x16x32_bf16(af, bfr, acc[nt], 0,0,0);
        }
    }
    #pragma unroll
    for (int nt=0;nt<4;++nt){
        float cc = c1[nt*16 + l15];
        #pragma unroll
        for (int q=0;q<4;++q){
            int rr = row0 + g*4 + q;
            if (rr < N) xbf[(size_t)rr*CH + nt*16 + l15] = f2bf(leakyf(acc[nt][q] + cc));
        }
    }
}

// ---------- prep: W0T scaled by a0, bf16: w0t[d][c] = a0[d]*W0[c][d] ----------
__global__ void prep_w0_kernel(const float* __restrict__ W0, const float* __restrict__ a0,
                               ushort* __restrict__ w0t)
{
    int i = blockIdx.x*256 + threadIdx.x;
    if (i < CH*CH){ int d = i >> 6, c = i & 63; w0t[i] = f2bf(a0[d]*W0[c*CH + d]); }
}

// ---------- prep: w1s[(c*64+h)][dd] = W1[dd][3h+c], bf16 ----------
__global__ void prep_w1_kernel(const float* __restrict__ W1, ushort* __restrict__ w1s)
{
    int i = blockIdx.x*256 + threadIdx.x;
    if (i < 192*CH){
        int r = i >> 6, dd = i & 63;
        int c = r >> 6, h = r & 63;
        w1s[i] = f2bf(W1[dd*192 + 3*h + c]);
    }
}

// ---------- prep: wcat[o][kk] = scaled concat(Wsc,Wu2)^T bf16 ; ccomb = csc+c2o ----------
__global__ void prep_final_kernel(const float* __restrict__ Wsc, const float* __restrict__ Wu2,
    const float* __restrict__ asc, const float* __restrict__ csc,
    const float* __restrict__ a2o, const float* __restrict__ c2o,
    ushort* __restrict__ wcat, float* __restrict__ ccomb)
{
    int i = blockIdx.x*256 + threadIdx.x;
    if (i < COUT*192){
        int o = i / 192, kk = i % 192;
        float v = (kk < CIN) ? asc[o]*Wsc[kk*COUT + o] : a2o[o]*Wu2[(kk-CIN)*COUT + o];
        wcat[i] = f2bf(v);
    }
    if (i < COUT) ccomb[i] = csc[i] + c2o[i];
}

// ---------- fused MFMA: gather -> conv0(swapped) -> bn0+leaky -> nbx-scaled k0c -> conv1 -> stats ----------
__global__ __launch_bounds__(512) void conv_msg_mfma(
    const ushort* __restrict__ xbf, const float* __restrict__ qp, const float* __restrict__ sp,
    const int* __restrict__ inds, const ushort* __restrict__ w0t, const ushort* __restrict__ w1s,
    const float* __restrict__ c0p,
    float* __restrict__ mx, float* __restrict__ mn, float* __restrict__ msgpart, int N)
{
    __shared__ unsigned char SM[24576 + 8*12288];   // Wstage (swizzled) + per-wave k0c tiles
    int tid = threadIdx.x;
    int warp = tid >> 6, lane = tid & 63;
    int l15 = lane & 15, g = lane >> 4;
    // stage w1s (192x64 bf16) into LDS, XOR-swizzled by row&7
    for (int ch = tid; ch < 1536; ch += 512){
        int r = ch >> 3, c16 = ch & 7;
        uint4 v = ((const uint4*)w1s)[ch];
        *(uint4*)(SM + r*128 + ((c16*16) ^ ((r&7)<<4))) = v;
    }
    // loop-invariant W0T fragments + c0
    bf16x8 wf[8];
    #pragma unroll
    for (int mt=0;mt<4;++mt)
        #pragma unroll
        for (int s=0;s<2;++s)
            wf[mt*2+s] = *(const bf16x8*)(w0t + (mt*16+l15)*CH + s*32 + g*8);
    float c0r[16];
    #pragma unroll
    for (int mt=0;mt<4;++mt)
        #pragma unroll
        for (int q=0;q<4;++q)
            c0r[mt*4+q] = c0p[mt*16 + g*4 + q];
    unsigned char* k0base = SM + 24576 + warp*12288;
    unsigned swz = (unsigned)((l15 & 7) << 4);
    float ps[4] = {0,0,0,0}, pss[4] = {0,0,0,0};
    const int nwaves = gridDim.x*8;
    const f32x4 z4 = {0.f,0.f,0.f,0.f};
    __syncthreads();

    for (int n = blockIdx.x*8 + warp; n < N; n += nwaves){
        int ix0 = inds[n*KNB + l15];
        int ix1 = inds[n*KNB + 16 + l15];
        if ((unsigned)ix0 > (unsigned)N) ix0 = N;
        if ((unsigned)ix1 > (unsigned)N) ix1 = N;
        float qx = qp[n*3+0], qy = qp[n*3+1], qz = qp[n*3+2];
        float nbv[2][3];
        if (ix0 < N){ nbv[0][0]=sp[ix0*3]-qx; nbv[0][1]=sp[ix0*3+1]-qy; nbv[0][2]=sp[ix0*3+2]-qz; }
        else        { nbv[0][0]=-qx; nbv[0][1]=-qy; nbv[0][2]=-qz; }
        if (ix1 < N){ nbv[1][0]=sp[ix1*3]-qx; nbv[1][1]=sp[ix1*3+1]-qy; nbv[1][2]=sp[ix1*3+2]-qz; }
        else        { nbv[1][0]=-qx; nbv[1][1]=-qy; nbv[1][2]=-qz; }
        // gather nb_y fragments (B operand of swapped conv0), 16B per lane
        bf16x8 xf0a = *(const bf16x8*)(xbf + (size_t)ix0*CH +      g*8);
        bf16x8 xf0b = *(const bf16x8*)(xbf + (size_t)ix0*CH + 32 + g*8);
        bf16x8 xf1a = *(const bf16x8*)(xbf + (size_t)ix1*CH +      g*8);
        bf16x8 xf1b = *(const bf16x8*)(xbf + (size_t)ix1*CH + 32 + g*8);
        // conv0: z0^T = (a0.W0^T) @ nb_y^T   (M=d:4 tiles, N=k:2 tiles, K=c:2 steps)
        f32x4 acc0[8];
        #pragma unroll
        for (int i=0;i<8;++i) acc0[i] = z4;
        #pragma unroll
        for (int mt=0;mt<4;++mt){
            acc0[mt*2+0] = __builtin_amdgcn_mfma_f32_16x16x32_bf16(wf[mt*2+0], xf0a, acc0[mt*2+0], 0,0,0);
            acc0[mt*2+0] = __builtin_amdgcn_mfma_f32_16x16x32_bf16(wf[mt*2+1], xf0b, acc0[mt*2+0], 0,0,0);
            acc0[mt*2+1] = __builtin_amdgcn_mfma_f32_16x16x32_bf16(wf[mt*2+0], xf1a, acc0[mt*2+1], 0,0,0);
            acc0[mt*2+1] = __builtin_amdgcn_mfma_f32_16x16x32_bf16(wf[mt*2+1], xf1b, acc0[mt*2+1], 0,0,0);
        }
        // bn0 (+c0) + leaky, scale by nbx[c], pack bf16, write k0c[c][k][d] (swizzled)
        #pragma unroll
        for (int mt=0;mt<4;++mt){
            #pragma unroll
            for (int ntk=0;ntk<2;++ntk){
                f32x4 a = acc0[mt*2+ntk];
                float v0 = leakyf(a[0] + c0r[mt*4+0]);
                float v1 = leakyf(a[1] + c0r[mt*4+1]);
                float v2 = leakyf(a[2] + c0r[mt*4+2]);
                float v3 = leakyf(a[3] + c0r[mt*4+3]);
                #pragma unroll
                for (int c=0;c<3;++c){
                    float w = nbv[ntk][c];
                    uint2 pk;
                    pk.x = cvtpk(v0*w, v1*w);
                    pk.y = cvtpk(v2*w, v3*w);
                    *(uint2*)(k0base + (c*32 + ntk*16 + l15)*128 + ((unsigned)(mt*32 + g*8) ^ swz)) = pk;
                }
            }
        }
        // conv1: msg = sum_c (k0*nbx_c) @ W1_c   (M=k:2 tiles, N=h:4 tiles, K=dd:2 steps, c:3)
        f32x4 acc1[8];
        #pragma unroll
        for (int i=0;i<8;++i) acc1[i] = z4;
        #pragma unroll
        for (int c=0;c<3;++c){
            #pragma unroll
            for (int ks=0;ks<2;++ks){
                unsigned co = ((unsigned)(ks*64 + g*16)) ^ swz;
                bf16x8 a0f = *(const bf16x8*)(k0base + (c*32 +      l15)*128 + co);
                bf16x8 a1f = *(const bf16x8*)(k0base + (c*32 + 16 + l15)*128 + co);
                #pragma unroll
                for (int nt=0;nt<4;++nt){
                    bf16x8 bfr = *(const bf16x8*)(SM + (c*64 + nt*16 + l15)*128 + co);
                    acc1[0*4+nt] = __builtin_amdgcn_mfma_f32_16x16x32_bf16(a0f, bfr, acc1[0*4+nt], 0,0,0);
                    acc1[1*4+nt] = __builtin_amdgcn_mfma_f32_16x16x32_bf16(a1f, bfr, acc1[1*4+nt], 0,0,0);
                }
            }
        }
        // reduce over k: per-lane 8 vals, then butterfly over lane>>4 groups
        #pragma unroll
        for (int nt=0;nt<4;++nt){
            float vmx = -3.4e38f, vmn = 3.4e38f, s = 0.f, ssq = 0.f;
            #pragma unroll
            for (int mtk=0;mtk<2;++mtk){
                f32x4 a = acc1[mtk*4+nt];
                #pragma unroll
                for (int q=0;q<4;++q){
                    float v = a[q];
                    vmx = fmaxf(vmx, v); vmn = fminf(vmn, v);
                    s += v; ssq += v*v;
                }
            }
            vmx = fmaxf(vmx, __shfl_xor(vmx, 16)); vmn = fminf(vmn, __shfl_xor(vmn, 16));
            s  += __shfl_xor(s, 16);               ssq += __shfl_xor(ssq, 16);
            vmx = fmaxf(vmx, __shfl_xor(vmx, 32)); vmn = fminf(vmn, __shfl_xor(vmn, 32));
            s  += __shfl_xor(s, 32);               ssq += __shfl_xor(ssq, 32);
            if (lane < 16){
                mx[(size_t)n*CH + nt*16 + l15] = vmx;
                mn[(size_t)n*CH + nt*16 + l15] = vmn;
                ps[nt] += s; pss[nt] += ssq;
            }
        }
    }
    // block-level stat reduction (reuse LDS)
    __syncthreads();
    float* red = (float*)SM;
    if (lane < 16){
        #pragma unroll
        for (int nt=0;nt<4;++nt){
            red[warp*128 + nt*16 + l15]        = ps[nt];
            red[1024 + warp*128 + nt*16 + l15] = pss[nt];
        }
    }
    __syncthreads();
    if (tid < 64){
        float s = 0.f, ssq = 0.f;
        #pragma unroll
        for (int w8=0;w8<8;++w8){ s += red[w8*128 + tid]; ssq += red[1024 + w8*128 + tid]; }
        msgpart[(size_t)blockIdx.x*128 + tid]      = s;
        msgpart[(size_t)blockIdx.x*128 + 64 + tid] = ssq;
    }
}

// ---------- agg = leaky(a1m*(max or min)+c1m) ; bnc stat partials ----------
__global__ __launch_bounds__(256) void msg_agg_kernel(const float* __restrict__ mx, const float* __restrict__ mn,
    const float* __restrict__ a1m, const float* __restrict__ c1m,
    float* __restrict__ agg, float* __restrict__ aggpart, int total)
{
    int tid = threadIdx.x; int h = tid & 63;
    float ah = a1m[h], ch = c1m[h];
    bool useMax = (ah >= 0.f);
    float ps = 0.f, pss = 0.f;
    for (int i = blockIdx.x*256 + tid; i < total; i += gridDim.x*256){
        float sel = useMax ? mx[i] : mn[i];
        float v = leakyf(ah*sel + ch);
        agg[i] = v; ps += v; pss += v*v;
    }
    __shared__ float r1[256], r2[256];
    r1[tid] = ps; r2[tid] = pss;
    __syncthreads();
    if (tid < 64){
        float s  = r1[tid] + r1[tid+64] + r1[tid+128] + r1[tid+192];
        float ss = r2[tid] + r2[tid+64] + r2[tid+128] + r2[tid+192];
        aggpart[(size_t)blockIdx.x*128 + tid]      = s;
        aggpart[(size_t)blockIdx.x*128 + 64 + tid] = ss;
    }
}

// ---------- final: out = leaky( [featbf|a2b2] @ wcat^T + ccomb ), bf16 MFMA ----------
__global__ __launch_bounds__(256) void final_mfma_kernel(
    const ushort* __restrict__ featbf, const ushort* __restrict__ a2b2,
    const ushort* __restrict__ wcat, const float* __restrict__ ccomb,
    float* __restrict__ out, int N)
{
    int tid = threadIdx.x, warp = tid >> 6, lane = tid & 63;
    int l15 = lane & 15, g = lane >> 4;
    int row0 = blockIdx.x*64 + warp*16;
    const f32x4 z4 = {0.f,0.f,0.f,0.f};
    f32x4 acc[16];
    #pragma unroll
    for (int i=0;i<16;++i) acc[i] = z4;
    int r = row0 + l15;
    bool ok = r < N;
    #pragma unroll
    for (int s=0;s<6;++s){
        bf16x8 af = {0,0,0,0,0,0,0,0};
        if (ok){
            const ushort* srcp = (s < 4) ? (featbf + (size_t)r*CIN + s*32 + g*8)
                                         : (a2b2  + (size_t)r*CH + (s-4)*32 + g*8);
            af = *(const bf16x8*)srcp;
        }
        #pragma unroll
        for (int nt=0;nt<16;++nt){
            bf16x8 bfr = *(const bf16x8*)(wcat + (nt*16+l15)*192 + s*32 + g*8);
            acc[nt] = __builtin_amdgcn_mfma_f32_16x16x32_bf16(af, bfr, acc[nt], 0,0,0);
        }
    }
    #pragma unroll
    for (int nt=0;nt<16;++nt){
        float cc = ccomb[nt*16 + l15];
        #pragma unroll
        for (int q=0;q<4;++q){
            int rr = row0 + g*4 + q;
            if (rr < N){
                float v = acc[nt][q] + cc;
                out[(size_t)rr*COUT + nt*16 + l15] = leakyf(v);
            }
        }
    }
}

extern "C" void kernel_launch(void* const* d_in, const int* in_sizes, int n_in,
                              void* d_out, int out_size, void* d_ws, size_t ws_size,
                              hipStream_t stream)
{
    const float* feat = (const float*)d_in[0];
    const float* qp   = (const float*)d_in[1];
    const float* sp   = (const float*)d_in[2];
    const int*   inds = (const int*)d_in[3];
    const float* Wu1  = (const float*)d_in[4];
    const float* g1   = (const float*)d_in[5];
    const float* b1   = (const float*)d_in[6];
    const float* W0   = (const float*)d_in[7];
    const float* gb0  = (const float*)d_in[8];
    const float* bb0  = (const float*)d_in[9];
    const float* W1   = (const float*)d_in[10];
    const float* gb1  = (const float*)d_in[11];
    const float* bb1  = (const float*)d_in[12];
    const float* gbc  = (const float*)d_in[13];
    const float* bbc  = (const float*)d_in[14];
    const float* Wu2  = (const float*)d_in[15];
    const float* g2   = (const float*)d_in[16];
    const float* b2   = (const float*)d_in[17];
    const float* Wsc  = (const float*)d_in[18];
    const float* gsc  = (const float*)d_in[19];
    const float* bsc  = (const float*)d_in[20];

    const int N = in_sizes[0] / CIN;           // 20000

    float* ws   = (float*)d_ws;
    float* XtX  = ws;                              // 16384 + 128 (G128 + fsum)
    float* fsum = XtX + 16384;
    float* G0   = XtX + 16512;                     // 4096 + 64
    float* s0   = G0 + 4096;
    float* G2   = G0 + 4160;                       // 4096 + 64
    float* s2   = G2 + 4096;
    float* cnt  = G2 + 4160;                       // N
    float* prm  = cnt + N;                         // 1536 params
    float* a1 = prm,      *c1 = prm+64,  *a0 = prm+128,  *c0 = prm+192;
    float* a1m = prm+256, *c1m = prm+320, *abnc = prm+384, *cbnc = prm+448;
    float* asc = prm+512, *csc = prm+768, *a2o = prm+1024, *c2o = prm+1280;
    float* msgpart = prm + 1536;                   // CONV_GRID*128
    float* aggpart = msgpart + CONV_GRID*128;      // AGG_GRID*128
    float* mxb  = aggpart + AGG_GRID*128;          // N*64
    float* mnb  = mxb  + (size_t)N*CH;             // N*64
    float* aggb = mnb  + (size_t)N*CH;             // N*64
    float* p    = aggb + (size_t)N*CH;
    ushort* xbf    = (ushort*)p;  p += (size_t)(N+1)*CH/2;   // (N+1)*64 bf16
    ushort* featbf = (ushort*)p;  p += (size_t)N*CIN/2;      // N*128 bf16
    ushort* a2b2   = (ushort*)p;  p += (size_t)N*CH/2;       // N*64 bf16
    ushort* w0t    = (ushort*)p;  p += 2048;                 // 64*64 bf16
    ushort* w1s    = (ushort*)p;  p += 6144;                 // 192*64 bf16
    ushort* wcat   = (ushort*)p;  p += 24576;                // 256*192 bf16
    ushort* w1t    = (ushort*)p;  p += 4096;                 // 64*128 bf16
    float*  ccomb  = p;                                      // 256 f32

    // Gram partial slabs alias dead regions (stream-order safe):
    //  slabA (128*16512 = 2.11M f) on mxb+mnb (2.56M f): dead until conv_msg.
    //  slabB (128*4160) on aggb: dead until msg_agg writes it (after reduce).
    //  slabC (128*4160) on mxb: dead after msg_agg reads it (gram64t runs later).
    float* slabA = mxb;
    float* slabB = aggb;
    float* slabC = mxb;

    hipMemsetAsync(cnt, 0, (size_t)N*sizeof(float), stream);
    hipMemsetAsync((void*)(xbf + (size_t)N*CH), 0, CH*sizeof(ushort), stream);  // zero shadow row

    cvt_bf16x4_kernel<<<(N*CIN/4 + 255)/256, 256, 0, stream>>>(feat, featbf, N*CIN/4);
    hist_kernel<<<(N*KNB + 255)/256, 256, 0, stream>>>(inds, N*KNB, N, cnt);
    prep_w1_kernel<<<48, 256, 0, stream>>>(W1, w1s);

    gram128_mfma<<<G128_GRID, 256, 0, stream>>>(featbf, N, slabA);
    reduce_slab<<<(16512 + 255)/256, 256, 0, stream>>>(slabA, G128_GRID, 16512, XtX);
    finalize_lin_bn<<<CH, 64, 0, stream>>>(XtX, fsum, Wu1, g1, b1, 1.0f/N, CIN, CH, a1, c1);
    finalize_lin_bn<<<COUT, 64, 0, stream>>>(XtX, fsum, Wsc, gsc, bsc, 1.0f/N, CIN, COUT, asc, csc);

    prep_u1_kernel<<<32, 256, 0, stream>>>(Wu1, a1, w1t);
    unary1_mfma<<<(N + 63)/64, 256, 0, stream>>>(featbf, w1t, c1, xbf, N);

    gram64w_mfma<<<G64_GRID, 256, 0, stream>>>(xbf, cnt, N, slabB);
    reduce_slab<<<(4160 + 255)/256, 256, 0, stream>>>(slabB, G64_GRID, 4160, G0);
    finalize_lin_bn<<<CH, 64, 0, stream>>>(G0, s0, W0, gb0, bb0, 1.0f/((float)N*KNB), CH, CH, a0, c0);
    prep_w0_kernel<<<16, 256, 0, stream>>>(W0, a0, w0t);

    conv_msg_mfma<<<CONV_GRID, 512, 0, stream>>>(xbf, qp, sp, inds, w0t, w1s, c0, mxb, mnb, msgpart, N);
    finalize_direct<<<1, 256, 0, stream>>>(msgpart, CONV_GRID, gb1, bb1, 1.0f/((float)N*KNB), a1m, c1m);
    msg_agg_kernel<<<AGG_GRID, 256, 0, stream>>>(mxb, mnb, a1m, c1m, aggb, aggpart, N*CH);
    finalize_direct<<<1, 256, 0, stream>>>(aggpart, AGG_GRID, gbc, bbc, 1.0f/N, abnc, cbnc);

    gram64t_mfma<<<G64_GRID, 256, 0, stream>>>(aggb, abnc, cbnc, a2b2, N, slabC);
    reduce_slab<<<(4160 + 255)/256, 256, 0, stream>>>(slabC, G64_GRID, 4160, G2);
    finalize_lin_bn<<<COUT, 64, 0, stream>>>(G2, s2, Wu2, g2, b2, 1.0f/N, CH, COUT, a2o, c2o);
    prep_final_kernel<<<192, 256, 0, stream>>>(Wsc, Wu2, asc, csc, a2o, c2o, wcat, ccomb);

    final_mfma_kernel<<<(N + 63)/64, 256, 0, stream>>>(featbf, a2b2, wcat, ccomb, (float*)d_out, N);
}